// Round 4
// baseline (733.597 us; speedup 1.0000x reference)
//
#include <hip/hip_runtime.h>
#include <hip/hip_fp16.h>

constexpr int N_NODES = 50000;
constexpr int N_EDGES = 800000;
constexpr int HIDDEN  = 128;
constexpr float RSQRT_D = 0.17677669529663687f;  // 1/sqrt(32)
constexpr int Y_SIZE = N_NODES * HIDDEN;         // 6,400,000
constexpr int M_PAD  = 50048;                    // 391 * 128

// ---- ws layout (float offsets) ----
constexpr size_t OFF_Q      = 0;
constexpr size_t OFF_K      = 6400000;   // fp16 kb lives here (12.8 MB of 25.6)
constexpr size_t OFF_V      = 12800000;  // fp16 vb lives here
constexpr size_t OFF_S      = 19200000;
constexpr size_t OFF_DENOM  = 25600000;  // N*4 floats; ALSO hosts Wt_swz (dead before k_fused)
constexpr size_t OFF_GSUM   = 25800000;  // 64
constexpr size_t OFF_GVAR   = 25800064;  // 64
constexpr size_t OFF_GCNT   = 25800128;  // 64 ints
constexpr size_t OFF_DEG    = 25800192;  // 50000 ints
constexpr size_t OFF_OFFS   = 25850192;  // 50001 ints
constexpr size_t OFF_CURSOR = 25900224;  // 50000 ints
constexpr size_t OFF_CSRSRC = 25950224;  // 800000 ints
constexpr size_t OFF_CSREID = 26750224;  // 800000 ints

typedef __attribute__((ext_vector_type(8))) short bf16x8;
typedef __attribute__((ext_vector_type(4))) float f32x4;

__device__ __forceinline__ short f2bf(float f) {  // RNE f32 -> bf16 bits
    unsigned u = __float_as_uint(f);
    unsigned r = (u + 0x7fff + ((u >> 16) & 1)) >> 16;
    return (short)r;
}

__device__ __forceinline__ void gload_lds16(const void* g, void* l) {
    __builtin_amdgcn_global_load_lds(
        (const __attribute__((address_space(1))) void*)g,
        (__attribute__((address_space(3))) void*)l, 16, 0, 0);
}

// ---------------- x f32 -> bf16, padded to M_PAD rows, XOR-swizzled ----------------
__global__ __launch_bounds__(256) void k_cvt_x(const float* __restrict__ x,
                                               short* __restrict__ xs)
{
    int tid = blockIdx.x * 256 + threadIdx.x;  // M_PAD*16 exact
    int row = tid >> 4, ci = tid & 15;
    short o[8];
    if (row < N_NODES) {
        float4 a = *(const float4*)&x[(size_t)row * 128 + ci * 8];
        float4 b = *(const float4*)&x[(size_t)row * 128 + ci * 8 + 4];
        o[0] = f2bf(a.x); o[1] = f2bf(a.y); o[2] = f2bf(a.z); o[3] = f2bf(a.w);
        o[4] = f2bf(b.x); o[5] = f2bf(b.y); o[6] = f2bf(b.z); o[7] = f2bf(b.w);
    } else {
        #pragma unroll
        for (int j = 0; j < 8; ++j) o[j] = 0;
    }
    int cs = ci ^ (row & 7);
    *(int4*)&xs[(size_t)row * 128 + cs * 8] = *(int4*)o;
}

// ---------------- W [K=128][N=128] f32 -> Wt bf16 [n][k], swizzled ----------------
__global__ __launch_bounds__(256) void k_cvt_w(
    const float* __restrict__ Wq, const float* __restrict__ Wk,
    const float* __restrict__ Wv, const float* __restrict__ Wsm,
    short* __restrict__ wt)
{
    int tid = blockIdx.x * 256 + threadIdx.x;  // 8192 exact
    int mat = tid >> 11, n = (tid >> 4) & 127, kg = tid & 15;
    const float* W = (mat == 0) ? Wq : (mat == 1) ? Wk : (mat == 2) ? Wv : Wsm;
    short o[8];
    #pragma unroll
    for (int j = 0; j < 8; ++j) o[j] = f2bf(W[(kg * 8 + j) * 128 + n]);
    int cs = kg ^ (n & 7);
    *(int4*)&wt[mat * 16384 + n * 128 + cs * 8] = *(int4*)o;
}

// ---------------- MFMA GEMM: q,s -> f32; k,v -> fp16 ----------------
__global__ __launch_bounds__(256) void k_mm(
    const short* __restrict__ xs, const short* __restrict__ wt,
    const float* __restrict__ bq, const float* __restrict__ bk,
    const float* __restrict__ bv, const float* __restrict__ bs,
    float* __restrict__ q, __half* __restrict__ kb,
    __half* __restrict__ vb, float* __restrict__ s)
{
    __shared__ __align__(16) char As[32768];
    __shared__ __align__(16) char Bs[32768];
    const int t = threadIdx.x, lane = t & 63, wv = t >> 6;
    const int bm = blockIdx.x >> 2, nt = blockIdx.x & 3;
    const int m0 = bm * 128;

    const char* gA = (const char*)xs + (size_t)m0 * 256;
    const char* gB = (const char*)wt + nt * 32768;
    #pragma unroll
    for (int i = 0; i < 8; ++i) {
        int chunk = wv * 8 + i;
        gload_lds16(gA + chunk * 1024 + lane * 16, As + chunk * 1024);
        gload_lds16(gB + chunk * 1024 + lane * 16, Bs + chunk * 1024);
    }

    const float* Bb = (nt == 0) ? bq : (nt == 1) ? bk : (nt == 2) ? bv : bs;
    const int wm = wv >> 1, wn = wv & 1;
    f32x4 acc[4][4];
    #pragma unroll
    for (int nf = 0; nf < 4; ++nf) {
        float bc = Bb[wn * 64 + nf * 16 + (lane & 15)];
        #pragma unroll
        for (int mf = 0; mf < 4; ++mf) acc[mf][nf] = (f32x4){bc, bc, bc, bc};
    }
    __syncthreads();

    #pragma unroll
    for (int ks = 0; ks < 4; ++ks) {
        bf16x8 af[4], bfr[4];
        const int cbase = ks * 64 + ((lane >> 4) << 4);
        #pragma unroll
        for (int mf = 0; mf < 4; ++mf) {
            int mr = wm * 64 + mf * 16 + (lane & 15);
            af[mf] = *(const bf16x8*)(As + mr * 256 + (cbase ^ ((mr & 7) << 4)));
        }
        #pragma unroll
        for (int nf = 0; nf < 4; ++nf) {
            int nc = wn * 64 + nf * 16 + (lane & 15);
            bfr[nf] = *(const bf16x8*)(Bs + nc * 256 + (cbase ^ ((nc & 7) << 4)));
        }
        #pragma unroll
        for (int mf = 0; mf < 4; ++mf)
            #pragma unroll
            for (int nf = 0; nf < 4; ++nf)
                acc[mf][nf] = __builtin_amdgcn_mfma_f32_16x16x32_bf16(
                    af[mf], bfr[nf], acc[mf][nf], 0, 0, 0);
    }

    const int colbase = wn * 64 + (lane & 15);
    if (nt == 0 || nt == 3) {
        float* O = (nt == 0) ? q : s;
        #pragma unroll
        for (int mf = 0; mf < 4; ++mf) {
            int rowb = m0 + wm * 64 + mf * 16 + ((lane >> 4) << 2);
            #pragma unroll
            for (int nf = 0; nf < 4; ++nf) {
                int col = colbase + nf * 16;
                #pragma unroll
                for (int r = 0; r < 4; ++r) {
                    int node = rowb + r;
                    if (node < N_NODES) O[(size_t)node * 128 + col] = acc[mf][nf][r];
                }
            }
        }
    } else {
        __half* O = (nt == 1) ? kb : vb;
        #pragma unroll
        for (int mf = 0; mf < 4; ++mf) {
            int rowb = m0 + wm * 64 + mf * 16 + ((lane >> 4) << 2);
            #pragma unroll
            for (int nf = 0; nf < 4; ++nf) {
                int col = colbase + nf * 16;
                #pragma unroll
                for (int r = 0; r < 4; ++r) {
                    int node = rowb + r;
                    if (node < N_NODES)
                        O[(size_t)node * 128 + col] = __float2half_rn(acc[mf][nf][r]);
                }
            }
        }
    }
}

// ---------------- CSR build: histogram / scan / scatter ----------------
__global__ __launch_bounds__(256) void k_hist(const int* __restrict__ dst,
                                              int* __restrict__ deg)
{
    int e = blockIdx.x * 256 + threadIdx.x;  // E exact
    atomicAdd(&deg[dst[e]], 1);
}

__global__ __launch_bounds__(1024) void k_scan(const int* __restrict__ deg,
                                               int* __restrict__ offs,
                                               int* __restrict__ cursor)
{
    __shared__ int part[1024];
    const int t = threadIdx.x;
    const int start = t * 49;          // 1024*49 = 50176 >= 50000
    int sum = 0;
    for (int i = 0; i < 49; ++i) {
        int idx = start + i;
        if (idx < N_NODES) sum += deg[idx];
    }
    part[t] = sum;
    __syncthreads();
    for (int off = 1; off < 1024; off <<= 1) {
        int tmp = (t >= off) ? part[t - off] : 0;
        __syncthreads();
        part[t] += tmp;
        __syncthreads();
    }
    int base = (t == 0) ? 0 : part[t - 1];
    for (int i = 0; i < 49; ++i) {
        int idx = start + i;
        if (idx < N_NODES) {
            offs[idx] = base;
            cursor[idx] = base;
            base += deg[idx];
        }
    }
    if (t == 1023) offs[N_NODES] = part[1023];
}

__global__ __launch_bounds__(256) void k_scatter(
    const int* __restrict__ src, const int* __restrict__ dst,
    int* __restrict__ cursor, int* __restrict__ csr_src, int* __restrict__ csr_eid)
{
    int e = blockIdx.x * 256 + threadIdx.x;  // E exact
    int d = dst[e];
    int pos = atomicAdd(&cursor[d], 1);
    csr_src[pos] = src[e];
    csr_eid[pos] = e;
}

// ---------------- fused: logits + exp + denom + aggregate + skip + graph-sum ----------------
// One 64-lane wave per dst node; lane l owns channels (2l, 2l+1); head = l>>4.
__global__ __launch_bounds__(256) void k_fused(
    const float* __restrict__ q, const __half2* __restrict__ kb,
    const __half2* __restrict__ vb, const float* __restrict__ s,
    const int* __restrict__ offs, const int* __restrict__ csr_src,
    const int* __restrict__ csr_eid, const int* __restrict__ batch,
    float* __restrict__ exbuf, float* __restrict__ denom,
    float* __restrict__ outb, float* __restrict__ gsum, int* __restrict__ gcnt)
{
    const int t = threadIdx.x;
    const int lane = t & 63;
    const int n = blockIdx.x * 4 + (t >> 6);  // grid*4 == N exact
    const int begin = offs[n], end = offs[n + 1];
    const float2 qv = *(const float2*)&q[(size_t)n * 128 + lane * 2];
    const int h = lane >> 4;
    float acc0 = 0.f, acc1 = 0.f, dsum = 0.f;
    int i = begin;
    for (; i + 2 <= end; i += 2) {
        const int sn0 = csr_src[i],     sn1 = csr_src[i + 1];
        const int e0  = csr_eid[i],     e1  = csr_eid[i + 1];
        const __half2 kh0 = kb[(size_t)sn0 * 64 + lane];
        const __half2 kh1 = kb[(size_t)sn1 * 64 + lane];
        const __half2 vh0 = vb[(size_t)sn0 * 64 + lane];
        const __half2 vh1 = vb[(size_t)sn1 * 64 + lane];
        const float2 k0 = __half22float2(kh0), k1 = __half22float2(kh1);
        float p0 = qv.x * k0.x + qv.y * k0.y;
        float p1 = qv.x * k1.x + qv.y * k1.y;
        p0 += __shfl_xor(p0, 1);  p1 += __shfl_xor(p1, 1);
        p0 += __shfl_xor(p0, 2);  p1 += __shfl_xor(p1, 2);
        p0 += __shfl_xor(p0, 4);  p1 += __shfl_xor(p1, 4);
        p0 += __shfl_xor(p0, 8);  p1 += __shfl_xor(p1, 8);
        const float ex0 = __expf(p0 * RSQRT_D);
        const float ex1 = __expf(p1 * RSQRT_D);
        dsum += ex0 + ex1;
        const float2 v0 = __half22float2(vh0), v1 = __half22float2(vh1);
        acc0 += ex0 * v0.x + ex1 * v1.x;
        acc1 += ex0 * v0.y + ex1 * v1.y;
        if ((lane & 15) == 0) {
            exbuf[e0 * 4 + h] = ex0;
            exbuf[e1 * 4 + h] = ex1;
        }
    }
    if (i < end) {
        const int sn0 = csr_src[i];
        const int e0  = csr_eid[i];
        const __half2 kh0 = kb[(size_t)sn0 * 64 + lane];
        const __half2 vh0 = vb[(size_t)sn0 * 64 + lane];
        const float2 k0 = __half22float2(kh0);
        float p0 = qv.x * k0.x + qv.y * k0.y;
        p0 += __shfl_xor(p0, 1);
        p0 += __shfl_xor(p0, 2);
        p0 += __shfl_xor(p0, 4);
        p0 += __shfl_xor(p0, 8);
        const float ex0 = __expf(p0 * RSQRT_D);
        dsum += ex0;
        const float2 v0 = __half22float2(vh0);
        acc0 += ex0 * v0.x;
        acc1 += ex0 * v0.y;
        if ((lane & 15) == 0) exbuf[e0 * 4 + h] = ex0;
    }
    if ((lane & 15) == 0) denom[n * 4 + h] = dsum;
    const float rdn = 1.f / (dsum + 1e-16f);
    const float2 sv = *(const float2*)&s[(size_t)n * 128 + lane * 2];
    float2 o = make_float2(acc0 * rdn + sv.x, acc1 * rdn + sv.y);
    *(float2*)&outb[(size_t)n * 128 + lane * 2] = o;

    // fused per-node -> per-graph sum & count
    float ls = o.x + o.y;
    ls += __shfl_xor(ls, 1);
    ls += __shfl_xor(ls, 2);
    ls += __shfl_xor(ls, 4);
    ls += __shfl_xor(ls, 8);
    ls += __shfl_xor(ls, 16);
    ls += __shfl_xor(ls, 32);
    if (lane == 0) {
        int g = batch[n];
        atomicAdd(&gsum[g], ls);
        atomicAdd(&gcnt[g], 1);
    }
}

// ---------------- normalize attn in place ----------------
__global__ __launch_bounds__(256) void k_norm(
    float* __restrict__ attn, const float* __restrict__ denom,
    const int* __restrict__ dst)
{
    int idx = blockIdx.x * 256 + threadIdx.x;  // E*4 exact
    int e = idx >> 2, h = idx & 3;
    attn[idx] = attn[idx] / (denom[dst[e] * 4 + h] + 1e-16f);
}

// ---------------- per-graph centered sum of squares ----------------
__global__ __launch_bounds__(256) void k_var(
    const float* __restrict__ out, const int* __restrict__ batch,
    const float* __restrict__ gsum, const int* __restrict__ gcnt,
    float* __restrict__ gvar)
{
    __shared__ float nsum[32];
    __shared__ int   ngr[32];
    const int t = threadIdx.x;
    const int nl = t >> 3, part = t & 7;
    const int n = blockIdx.x * 32 + nl;
    float lsum = 0.f;
    if (n < N_NODES) {
        int g = batch[n];
        float mean = gsum[g] / (fmaxf((float)gcnt[g], 1.f) * 128.f);
        size_t base = (size_t)n * 128 + part * 16;
        #pragma unroll
        for (int i = 0; i < 4; ++i) {
            float4 o = *(const float4*)&out[base + i * 4];
            float dx = o.x - mean, dy = o.y - mean, dz = o.z - mean, dw = o.w - mean;
            lsum += dx * dx + dy * dy + dz * dz + dw * dw;
        }
    }
    lsum += __shfl_xor(lsum, 1);
    lsum += __shfl_xor(lsum, 2);
    lsum += __shfl_xor(lsum, 4);
    if (part == 0) { nsum[nl] = lsum; ngr[nl] = (n < N_NODES) ? batch[n] : -1; }
    __syncthreads();
    if (t == 0) {
        float acc = 0.f; int cg = ngr[0];
        for (int i = 0; i < 32; ++i) {
            int g = ngr[i];
            if (g != cg) {
                if (cg >= 0) atomicAdd(&gvar[cg], acc);
                acc = 0.f; cg = g;
            }
            acc += nsum[i];
        }
        if (cg >= 0) atomicAdd(&gvar[cg], acc);
    }
}

// ---------------- LayerNorm affine + LeakyReLU (in-place) ----------------
__global__ __launch_bounds__(256) void k_final(
    const float* __restrict__ out, const int* __restrict__ batch,
    const float* __restrict__ gsum, const float* __restrict__ gvar,
    const int* __restrict__ gcnt,
    const float* __restrict__ lnw, const float* __restrict__ lnb,
    float* __restrict__ y)
{
    int idx = blockIdx.x * 256 + threadIdx.x;  // N*128 exact
    int n = idx >> 7, c = idx & 127;
    int g = batch[n];
    float norm = fmaxf((float)gcnt[g], 1.f) * 128.f;
    float mean = gsum[g] / norm;
    float var  = gvar[g] / norm;
    float inv  = rsqrtf(var + 1e-5f);
    float val  = (out[idx] - mean) * inv * lnw[c] + lnb[c];
    y[idx] = val > 0.f ? val : 0.01f * val;
}

extern "C" void kernel_launch(void* const* d_in, const int* in_sizes, int n_in,
                              void* d_out, int out_size, void* d_ws, size_t ws_size,
                              hipStream_t stream)
{
    (void)in_sizes; (void)n_in; (void)out_size; (void)ws_size;
    const float* x    = (const float*)d_in[0];
    const int*   ei   = (const int*)  d_in[1];
    const int*   batch= (const int*)  d_in[2];
    const float* Wq   = (const float*)d_in[3];
    const float* bq   = (const float*)d_in[4];
    const float* Wk   = (const float*)d_in[5];
    const float* bk   = (const float*)d_in[6];
    const float* Wv   = (const float*)d_in[7];
    const float* bv   = (const float*)d_in[8];
    const float* Wsm  = (const float*)d_in[9];
    const float* bs   = (const float*)d_in[10];
    const float* lnw  = (const float*)d_in[11];
    const float* lnb  = (const float*)d_in[12];

    float* outp = (float*)d_out;
    float* ws   = (float*)d_ws;

    const int* srcI = ei;
    const int* dstI = ei + N_EDGES;

    float*  q       = ws + OFF_Q;
    __half* kb      = (__half*)(ws + OFF_K);
    __half* vb      = (__half*)(ws + OFF_V);
    float*  s       = ws + OFF_S;
    float*  denom   = ws + OFF_DENOM;
    short*  wt      = (short*)(ws + OFF_DENOM);  // dead before k_fused writes denom
    float*  gsum    = ws + OFF_GSUM;
    float*  gvar    = ws + OFF_GVAR;
    int*    gcnt    = (int*)(ws + OFF_GCNT);
    int*    deg     = (int*)(ws + OFF_DEG);
    int*    offs    = (int*)(ws + OFF_OFFS);
    int*    cursor  = (int*)(ws + OFF_CURSOR);
    int*    csr_src = (int*)(ws + OFF_CSRSRC);
    int*    csr_eid = (int*)(ws + OFF_CSREID);

    float* outb  = outp;                  // y region: x_swz first, then pre-LN out
    short* x_swz = (short*)outp;          // 12.8 MB, dead once k_mm finishes
    float* attn  = outp + Y_SIZE;

    // zero gsum/gvar/gcnt + deg
    hipMemsetAsync(gsum, 0, (size_t)(192 + N_NODES) * sizeof(float), stream);

    k_cvt_w<<<32, 256, 0, stream>>>(Wq, Wk, Wv, Wsm, wt);
    k_cvt_x<<<(M_PAD * 16) / 256, 256, 0, stream>>>(x, x_swz);
    k_mm<<<(M_PAD / 128) * 4, 256, 0, stream>>>(x_swz, wt, bq, bk, bv, bs,
                                                q, kb, vb, s);

    k_hist<<<N_EDGES / 256, 256, 0, stream>>>(dstI, deg);
    k_scan<<<1, 1024, 0, stream>>>(deg, offs, cursor);
    k_scatter<<<N_EDGES / 256, 256, 0, stream>>>(srcI, dstI, cursor, csr_src, csr_eid);
    k_fused<<<N_NODES / 4, 256, 0, stream>>>(q, (const __half2*)kb, (const __half2*)vb,
                                             s, offs, csr_src, csr_eid, batch,
                                             attn, denom, outb, gsum, gcnt);
    k_norm<<<(N_EDGES * 4) / 256, 256, 0, stream>>>(attn, denom, dstI);
    k_var<<<(N_NODES + 31) / 32, 256, 0, stream>>>(outb, batch, gsum, gcnt, gvar);
    k_final<<<Y_SIZE / 256, 256, 0, stream>>>(outb, batch, gsum, gvar, gcnt,
                                              lnw, lnb, outp);
}

// Round 5
// 390.227 us; speedup vs baseline: 1.8799x; 1.8799x over previous
//
#include <hip/hip_runtime.h>
#include <hip/hip_fp16.h>

constexpr int N_NODES = 50000;
constexpr int N_EDGES = 800000;
constexpr int HIDDEN  = 128;
constexpr float RSQRT_D = 0.17677669529663687f;  // 1/sqrt(32)
constexpr int Y_SIZE = N_NODES * HIDDEN;         // 6,400,000
constexpr int M_PAD  = 50048;                    // 391 * 128

// ---- ws layout (float offsets) ----
constexpr size_t OFF_Q      = 0;
constexpr size_t OFF_K      = 6400000;   // fp16 kb (12.8 MB of the 25.6 MB slot)
constexpr size_t OFF_V      = 12800000;  // fp16 vb
constexpr size_t OFF_S      = 19200000;
constexpr size_t OFF_DENOM  = 25600000;  // N*4 floats; ALSO hosts Wt_swz (dead before k_fused)
constexpr size_t OFF_GSUM   = 25800000;  // 64
constexpr size_t OFF_GVAR   = 25800064;  // 64
constexpr size_t OFF_GCNT   = 25800128;  // 64 ints
constexpr size_t OFF_DEG    = 25800192;  // 50000 ints
constexpr size_t OFF_OFFS   = 25850192;  // 50001 ints
constexpr size_t OFF_CURSOR = 25900224;  // 50000 ints
constexpr size_t OFF_CSRSRC = 25950224;  // 800000 ints
constexpr size_t OFF_CSREID = 26750224;  // 800000 ints

typedef __attribute__((ext_vector_type(8))) short bf16x8;
typedef __attribute__((ext_vector_type(4))) float f32x4;

__device__ __forceinline__ short f2bf(float f) {  // RNE f32 -> bf16 bits
    unsigned u = __float_as_uint(f);
    unsigned r = (u + 0x7fff + ((u >> 16) & 1)) >> 16;
    return (short)r;
}

__device__ __forceinline__ void gload_lds16(const void* g, void* l) {
    __builtin_amdgcn_global_load_lds(
        (const __attribute__((address_space(1))) void*)g,
        (__attribute__((address_space(3))) void*)l, 16, 0, 0);
}

// ---------------- x f32 -> bf16, padded to M_PAD rows, XOR-swizzled ----------------
__global__ __launch_bounds__(256) void k_cvt_x(const float* __restrict__ x,
                                               short* __restrict__ xs)
{
    int tid = blockIdx.x * 256 + threadIdx.x;  // M_PAD*16 exact
    int row = tid >> 4, ci = tid & 15;
    short o[8];
    if (row < N_NODES) {
        float4 a = *(const float4*)&x[(size_t)row * 128 + ci * 8];
        float4 b = *(const float4*)&x[(size_t)row * 128 + ci * 8 + 4];
        o[0] = f2bf(a.x); o[1] = f2bf(a.y); o[2] = f2bf(a.z); o[3] = f2bf(a.w);
        o[4] = f2bf(b.x); o[5] = f2bf(b.y); o[6] = f2bf(b.z); o[7] = f2bf(b.w);
    } else {
        #pragma unroll
        for (int j = 0; j < 8; ++j) o[j] = 0;
    }
    int cs = ci ^ (row & 7);
    *(int4*)&xs[(size_t)row * 128 + cs * 8] = *(int4*)o;
}

// ---------------- W [K=128][N=128] f32 -> Wt bf16 [n][k], swizzled ----------------
__global__ __launch_bounds__(256) void k_cvt_w(
    const float* __restrict__ Wq, const float* __restrict__ Wk,
    const float* __restrict__ Wv, const float* __restrict__ Wsm,
    short* __restrict__ wt)
{
    int tid = blockIdx.x * 256 + threadIdx.x;  // 8192 exact
    int mat = tid >> 11, n = (tid >> 4) & 127, kg = tid & 15;
    const float* W = (mat == 0) ? Wq : (mat == 1) ? Wk : (mat == 2) ? Wv : Wsm;
    short o[8];
    #pragma unroll
    for (int j = 0; j < 8; ++j) o[j] = f2bf(W[(kg * 8 + j) * 128 + n]);
    int cs = kg ^ (n & 7);
    *(int4*)&wt[mat * 16384 + n * 128 + cs * 8] = *(int4*)o;
}

// ---------------- MFMA GEMM: q,s -> f32; k,v -> fp16 ----------------
__global__ __launch_bounds__(256) void k_mm(
    const short* __restrict__ xs, const short* __restrict__ wt,
    const float* __restrict__ bq, const float* __restrict__ bk,
    const float* __restrict__ bv, const float* __restrict__ bs,
    float* __restrict__ q, __half* __restrict__ kb,
    __half* __restrict__ vb, float* __restrict__ s)
{
    __shared__ __align__(16) char As[32768];
    __shared__ __align__(16) char Bs[32768];
    const int t = threadIdx.x, lane = t & 63, wv = t >> 6;
    const int bm = blockIdx.x >> 2, nt = blockIdx.x & 3;
    const int m0 = bm * 128;

    const char* gA = (const char*)xs + (size_t)m0 * 256;
    const char* gB = (const char*)wt + nt * 32768;
    #pragma unroll
    for (int i = 0; i < 8; ++i) {
        int chunk = wv * 8 + i;
        gload_lds16(gA + chunk * 1024 + lane * 16, As + chunk * 1024);
        gload_lds16(gB + chunk * 1024 + lane * 16, Bs + chunk * 1024);
    }

    const float* Bb = (nt == 0) ? bq : (nt == 1) ? bk : (nt == 2) ? bv : bs;
    const int wm = wv >> 1, wn = wv & 1;
    f32x4 acc[4][4];
    #pragma unroll
    for (int nf = 0; nf < 4; ++nf) {
        float bc = Bb[wn * 64 + nf * 16 + (lane & 15)];
        #pragma unroll
        for (int mf = 0; mf < 4; ++mf) acc[mf][nf] = (f32x4){bc, bc, bc, bc};
    }
    __syncthreads();

    #pragma unroll
    for (int ks = 0; ks < 4; ++ks) {
        bf16x8 af[4], bfr[4];
        const int cbase = ks * 64 + ((lane >> 4) << 4);
        #pragma unroll
        for (int mf = 0; mf < 4; ++mf) {
            int mr = wm * 64 + mf * 16 + (lane & 15);
            af[mf] = *(const bf16x8*)(As + mr * 256 + (cbase ^ ((mr & 7) << 4)));
        }
        #pragma unroll
        for (int nf = 0; nf < 4; ++nf) {
            int nc = wn * 64 + nf * 16 + (lane & 15);
            bfr[nf] = *(const bf16x8*)(Bs + nc * 256 + (cbase ^ ((nc & 7) << 4)));
        }
        #pragma unroll
        for (int mf = 0; mf < 4; ++mf)
            #pragma unroll
            for (int nf = 0; nf < 4; ++nf)
                acc[mf][nf] = __builtin_amdgcn_mfma_f32_16x16x32_bf16(
                    af[mf], bfr[nf], acc[mf][nf], 0, 0, 0);
    }

    const int colbase = wn * 64 + (lane & 15);
    if (nt == 0 || nt == 3) {
        float* O = (nt == 0) ? q : s;
        #pragma unroll
        for (int mf = 0; mf < 4; ++mf) {
            int rowb = m0 + wm * 64 + mf * 16 + ((lane >> 4) << 2);
            #pragma unroll
            for (int nf = 0; nf < 4; ++nf) {
                int col = colbase + nf * 16;
                #pragma unroll
                for (int r = 0; r < 4; ++r) {
                    int node = rowb + r;
                    if (node < N_NODES) O[(size_t)node * 128 + col] = acc[mf][nf][r];
                }
            }
        }
    } else {
        __half* O = (nt == 1) ? kb : vb;
        #pragma unroll
        for (int mf = 0; mf < 4; ++mf) {
            int rowb = m0 + wm * 64 + mf * 16 + ((lane >> 4) << 2);
            #pragma unroll
            for (int nf = 0; nf < 4; ++nf) {
                int col = colbase + nf * 16;
                #pragma unroll
                for (int r = 0; r < 4; ++r) {
                    int node = rowb + r;
                    if (node < N_NODES)
                        O[(size_t)node * 128 + col] = __float2half_rn(acc[mf][nf][r]);
                }
            }
        }
    }
}

// ---------------- CSR build: histogram / scan / scatter ----------------
__global__ __launch_bounds__(256) void k_hist(const int* __restrict__ dst,
                                              int* __restrict__ deg)
{
    int e = blockIdx.x * 256 + threadIdx.x;  // E exact
    atomicAdd(&deg[dst[e]], 1);
}

__global__ __launch_bounds__(1024) void k_scan(const int* __restrict__ deg,
                                               int* __restrict__ offs,
                                               int* __restrict__ cursor)
{
    __shared__ int part[1024];
    const int t = threadIdx.x;
    const int start = t * 49;          // 1024*49 = 50176 >= 50000
    int sum = 0;
    for (int i = 0; i < 49; ++i) {
        int idx = start + i;
        if (idx < N_NODES) sum += deg[idx];
    }
    part[t] = sum;
    __syncthreads();
    for (int off = 1; off < 1024; off <<= 1) {
        int tmp = (t >= off) ? part[t - off] : 0;
        __syncthreads();
        part[t] += tmp;
        __syncthreads();
    }
    int base = (t == 0) ? 0 : part[t - 1];
    for (int i = 0; i < 49; ++i) {
        int idx = start + i;
        if (idx < N_NODES) {
            offs[idx] = base;
            cursor[idx] = base;
            base += deg[idx];
        }
    }
    if (t == 1023) offs[N_NODES] = part[1023];
}

__global__ __launch_bounds__(256) void k_scatter(
    const int* __restrict__ src, const int* __restrict__ dst,
    int* __restrict__ cursor, int* __restrict__ csr_src, int* __restrict__ csr_eid)
{
    int e = blockIdx.x * 256 + threadIdx.x;  // E exact
    int d = dst[e];
    int pos = atomicAdd(&cursor[d], 1);
    csr_src[pos] = src[e];
    csr_eid[pos] = e;
}

// ---------------- fused: logits + exp + denom + aggregate + skip ----------------
// One 64-lane wave per dst node; lane l owns channels (2l, 2l+1); head = l>>4.
// NO contended atomics here (round-4 lesson: 100K same-line atomics cost ~250us).
__global__ __launch_bounds__(256) void k_fused(
    const float* __restrict__ q, const __half2* __restrict__ kb,
    const __half2* __restrict__ vb, const float* __restrict__ s,
    const int* __restrict__ offs, const int* __restrict__ csr_src,
    const int* __restrict__ csr_eid,
    float* __restrict__ exbuf, float* __restrict__ denom,
    float* __restrict__ outb)
{
    const int t = threadIdx.x;
    const int lane = t & 63;
    const int n = blockIdx.x * 4 + (t >> 6);  // grid*4 == N exact
    const int begin = offs[n], end = offs[n + 1];
    const float2 qv = *(const float2*)&q[(size_t)n * 128 + lane * 2];
    const int h = lane >> 4;
    float acc0 = 0.f, acc1 = 0.f, dsum = 0.f;
    int i = begin;
    // unroll x4: issue all 8 index loads, then all 8 row loads, then consume
    for (; i + 4 <= end; i += 4) {
        int sn[4], eid[4];
        #pragma unroll
        for (int u = 0; u < 4; ++u) { sn[u] = csr_src[i + u]; eid[u] = csr_eid[i + u]; }
        __half2 kh[4], vh[4];
        #pragma unroll
        for (int u = 0; u < 4; ++u) kh[u] = kb[(size_t)sn[u] * 64 + lane];
        #pragma unroll
        for (int u = 0; u < 4; ++u) vh[u] = vb[(size_t)sn[u] * 64 + lane];
        float p[4];
        #pragma unroll
        for (int u = 0; u < 4; ++u) {
            float2 kf = __half22float2(kh[u]);
            p[u] = qv.x * kf.x + qv.y * kf.y;
        }
        #pragma unroll
        for (int u = 0; u < 4; ++u) p[u] += __shfl_xor(p[u], 1);
        #pragma unroll
        for (int u = 0; u < 4; ++u) p[u] += __shfl_xor(p[u], 2);
        #pragma unroll
        for (int u = 0; u < 4; ++u) p[u] += __shfl_xor(p[u], 4);
        #pragma unroll
        for (int u = 0; u < 4; ++u) p[u] += __shfl_xor(p[u], 8);
        #pragma unroll
        for (int u = 0; u < 4; ++u) {
            float ex = __expf(p[u] * RSQRT_D);
            dsum += ex;
            float2 vf = __half22float2(vh[u]);
            acc0 += ex * vf.x;
            acc1 += ex * vf.y;
            if ((lane & 15) == 0) exbuf[eid[u] * 4 + h] = ex;
        }
    }
    for (; i < end; ++i) {
        const int sn0 = csr_src[i];
        const int e0  = csr_eid[i];
        const __half2 kh0 = kb[(size_t)sn0 * 64 + lane];
        const __half2 vh0 = vb[(size_t)sn0 * 64 + lane];
        const float2 k0 = __half22float2(kh0);
        float p0 = qv.x * k0.x + qv.y * k0.y;
        p0 += __shfl_xor(p0, 1);
        p0 += __shfl_xor(p0, 2);
        p0 += __shfl_xor(p0, 4);
        p0 += __shfl_xor(p0, 8);
        const float ex0 = __expf(p0 * RSQRT_D);
        dsum += ex0;
        const float2 v0 = __half22float2(vh0);
        acc0 += ex0 * v0.x;
        acc1 += ex0 * v0.y;
        if ((lane & 15) == 0) exbuf[e0 * 4 + h] = ex0;
    }
    if ((lane & 15) == 0) denom[n * 4 + h] = dsum;
    const float rdn = 1.f / (dsum + 1e-16f);
    const float2 sv = *(const float2*)&s[(size_t)n * 128 + lane * 2];
    float2 o = make_float2(acc0 * rdn + sv.x, acc1 * rdn + sv.y);
    *(float2*)&outb[(size_t)n * 128 + lane * 2] = o;
}

// ---------------- normalize attn in place ----------------
__global__ __launch_bounds__(256) void k_norm(
    float* __restrict__ attn, const float* __restrict__ denom,
    const int* __restrict__ dst)
{
    int idx = blockIdx.x * 256 + threadIdx.x;  // E*4 exact
    int e = idx >> 2, h = idx & 3;
    attn[idx] = attn[idx] / (denom[dst[e] * 4 + h] + 1e-16f);
}

// ---------------- per-graph sum & count (run-length -> few atomics) ----------------
__global__ __launch_bounds__(256) void k_sum(
    const float* __restrict__ out, const int* __restrict__ batch,
    float* __restrict__ gsum, int* __restrict__ gcnt)
{
    __shared__ float nsum[32];
    __shared__ int   ngr[32];
    const int t = threadIdx.x;
    const int nl = t >> 3, part = t & 7;
    const int n = blockIdx.x * 32 + nl;
    float lsum = 0.f;
    if (n < N_NODES) {
        size_t base = (size_t)n * 128 + part * 16;
        #pragma unroll
        for (int i = 0; i < 4; ++i) {
            float4 o = *(const float4*)&out[base + i * 4];
            lsum += o.x + o.y + o.z + o.w;
        }
    }
    lsum += __shfl_xor(lsum, 1);
    lsum += __shfl_xor(lsum, 2);
    lsum += __shfl_xor(lsum, 4);
    if (part == 0) { nsum[nl] = lsum; ngr[nl] = (n < N_NODES) ? batch[n] : -1; }
    __syncthreads();
    if (t == 0) {
        float acc = 0.f; int cg = ngr[0], cnt = 0;
        for (int i = 0; i < 32; ++i) {
            int g = ngr[i];
            if (g != cg) {
                if (cg >= 0) { atomicAdd(&gsum[cg], acc); atomicAdd(&gcnt[cg], cnt); }
                acc = 0.f; cnt = 0; cg = g;
            }
            acc += nsum[i]; ++cnt;
        }
        if (cg >= 0) { atomicAdd(&gsum[cg], acc); atomicAdd(&gcnt[cg], cnt); }
    }
}

// ---------------- per-graph centered sum of squares ----------------
__global__ __launch_bounds__(256) void k_var(
    const float* __restrict__ out, const int* __restrict__ batch,
    const float* __restrict__ gsum, const int* __restrict__ gcnt,
    float* __restrict__ gvar)
{
    __shared__ float nsum[32];
    __shared__ int   ngr[32];
    const int t = threadIdx.x;
    const int nl = t >> 3, part = t & 7;
    const int n = blockIdx.x * 32 + nl;
    float lsum = 0.f;
    if (n < N_NODES) {
        int g = batch[n];
        float mean = gsum[g] / (fmaxf((float)gcnt[g], 1.f) * 128.f);
        size_t base = (size_t)n * 128 + part * 16;
        #pragma unroll
        for (int i = 0; i < 4; ++i) {
            float4 o = *(const float4*)&out[base + i * 4];
            float dx = o.x - mean, dy = o.y - mean, dz = o.z - mean, dw = o.w - mean;
            lsum += dx * dx + dy * dy + dz * dz + dw * dw;
        }
    }
    lsum += __shfl_xor(lsum, 1);
    lsum += __shfl_xor(lsum, 2);
    lsum += __shfl_xor(lsum, 4);
    if (part == 0) { nsum[nl] = lsum; ngr[nl] = (n < N_NODES) ? batch[n] : -1; }
    __syncthreads();
    if (t == 0) {
        float acc = 0.f; int cg = ngr[0];
        for (int i = 0; i < 32; ++i) {
            int g = ngr[i];
            if (g != cg) {
                if (cg >= 0) atomicAdd(&gvar[cg], acc);
                acc = 0.f; cg = g;
            }
            acc += nsum[i];
        }
        if (cg >= 0) atomicAdd(&gvar[cg], acc);
    }
}

// ---------------- LayerNorm affine + LeakyReLU (in-place) ----------------
__global__ __launch_bounds__(256) void k_final(
    const float* __restrict__ out, const int* __restrict__ batch,
    const float* __restrict__ gsum, const float* __restrict__ gvar,
    const int* __restrict__ gcnt,
    const float* __restrict__ lnw, const float* __restrict__ lnb,
    float* __restrict__ y)
{
    int idx = blockIdx.x * 256 + threadIdx.x;  // N*128 exact
    int n = idx >> 7, c = idx & 127;
    int g = batch[n];
    float norm = fmaxf((float)gcnt[g], 1.f) * 128.f;
    float mean = gsum[g] / norm;
    float var  = gvar[g] / norm;
    float inv  = rsqrtf(var + 1e-5f);
    float val  = (out[idx] - mean) * inv * lnw[c] + lnb[c];
    y[idx] = val > 0.f ? val : 0.01f * val;
}

extern "C" void kernel_launch(void* const* d_in, const int* in_sizes, int n_in,
                              void* d_out, int out_size, void* d_ws, size_t ws_size,
                              hipStream_t stream)
{
    (void)in_sizes; (void)n_in; (void)out_size; (void)ws_size;
    const float* x    = (const float*)d_in[0];
    const int*   ei   = (const int*)  d_in[1];
    const int*   batch= (const int*)  d_in[2];
    const float* Wq   = (const float*)d_in[3];
    const float* bq   = (const float*)d_in[4];
    const float* Wk   = (const float*)d_in[5];
    const float* bk   = (const float*)d_in[6];
    const float* Wv   = (const float*)d_in[7];
    const float* bv   = (const float*)d_in[8];
    const float* Wsm  = (const float*)d_in[9];
    const float* bs   = (const float*)d_in[10];
    const float* lnw  = (const float*)d_in[11];
    const float* lnb  = (const float*)d_in[12];

    float* outp = (float*)d_out;
    float* ws   = (float*)d_ws;

    const int* srcI = ei;
    const int* dstI = ei + N_EDGES;

    float*  q       = ws + OFF_Q;
    __half* kb      = (__half*)(ws + OFF_K);
    __half* vb      = (__half*)(ws + OFF_V);
    float*  s       = ws + OFF_S;
    float*  denom   = ws + OFF_DENOM;
    short*  wt      = (short*)(ws + OFF_DENOM);  // dead before k_fused writes denom
    float*  gsum    = ws + OFF_GSUM;
    float*  gvar    = ws + OFF_GVAR;
    int*    gcnt    = (int*)(ws + OFF_GCNT);
    int*    deg     = (int*)(ws + OFF_DEG);
    int*    offs    = (int*)(ws + OFF_OFFS);
    int*    cursor  = (int*)(ws + OFF_CURSOR);
    int*    csr_src = (int*)(ws + OFF_CSRSRC);
    int*    csr_eid = (int*)(ws + OFF_CSREID);

    float* outb  = outp;                  // y region: x_swz first, then pre-LN out
    short* x_swz = (short*)outp;          // 12.8 MB, dead once k_mm finishes
    float* attn  = outp + Y_SIZE;

    // zero gsum/gvar/gcnt + deg
    hipMemsetAsync(gsum, 0, (size_t)(192 + N_NODES) * sizeof(float), stream);

    k_cvt_w<<<32, 256, 0, stream>>>(Wq, Wk, Wv, Wsm, wt);
    k_cvt_x<<<(M_PAD * 16) / 256, 256, 0, stream>>>(x, x_swz);
    k_mm<<<(M_PAD / 128) * 4, 256, 0, stream>>>(x_swz, wt, bq, bk, bv, bs,
                                                q, kb, vb, s);

    k_hist<<<N_EDGES / 256, 256, 0, stream>>>(dstI, deg);
    k_scan<<<1, 1024, 0, stream>>>(deg, offs, cursor);
    k_scatter<<<N_EDGES / 256, 256, 0, stream>>>(srcI, dstI, cursor, csr_src, csr_eid);
    k_fused<<<N_NODES / 4, 256, 0, stream>>>(q, (const __half2*)kb, (const __half2*)vb,
                                             s, offs, csr_src, csr_eid,
                                             attn, denom, outb);
    k_norm<<<(N_EDGES * 4) / 256, 256, 0, stream>>>(attn, denom, dstI);
    k_sum<<<(N_NODES + 31) / 32, 256, 0, stream>>>(outb, batch, gsum, gcnt);
    k_var<<<(N_NODES + 31) / 32, 256, 0, stream>>>(outb, batch, gsum, gcnt, gvar);
    k_final<<<Y_SIZE / 256, 256, 0, stream>>>(outb, batch, gsum, gvar, gcnt,
                                              lnw, lnb, outp);
}

// Round 6
// 272.645 us; speedup vs baseline: 2.6907x; 1.4313x over previous
//
#include <hip/hip_runtime.h>
#include <hip/hip_fp16.h>

constexpr int N_NODES = 50000;
constexpr int N_EDGES = 800000;
constexpr int HIDDEN  = 128;
constexpr float RSQRT_D = 0.17677669529663687f;  // 1/sqrt(32)
constexpr int Y_SIZE = N_NODES * HIDDEN;         // 6,400,000
constexpr int M_PAD  = 50048;                    // 391 * 128
constexpr int SCAN_BLOCKS = 196;                 // 196*256 = 50176 >= N_NODES

// ---- ws layout (float offsets) ----
constexpr size_t OFF_Q      = 0;
constexpr size_t OFF_K      = 6400000;   // fp16 kb (12.8 MB of the 25.6 MB slot)
constexpr size_t OFF_V      = 12800000;  // fp16 vb
constexpr size_t OFF_S      = 19200000;
constexpr size_t OFF_DENOM  = 25600000;  // N*4 floats; ALSO hosts Wt_swz (dead before k_fused)
constexpr size_t OFF_GSUM   = 25800000;  // 64
constexpr size_t OFF_GVAR   = 25800064;  // 64
constexpr size_t OFF_GCNT   = 25800128;  // 64 ints
constexpr size_t OFF_DEG    = 25800192;  // 50000 ints
constexpr size_t OFF_OFFS   = 25850192;  // 50001 ints
constexpr size_t OFF_CURSOR = 25900224;  // 50000 ints
constexpr size_t OFF_CSRSRC = 25950224;  // 800000 ints
constexpr size_t OFF_CSREID = 26750224;  // 800000 ints
constexpr size_t OFF_PART   = 27550224;  // 196 ints (scan partials)

typedef __attribute__((ext_vector_type(8))) short bf16x8;
typedef __attribute__((ext_vector_type(4))) float f32x4;

__device__ __forceinline__ short f2bf(float f) {  // RNE f32 -> bf16 bits
    unsigned u = __float_as_uint(f);
    unsigned r = (u + 0x7fff + ((u >> 16) & 1)) >> 16;
    return (short)r;
}

__device__ __forceinline__ void gload_lds16(const void* g, void* l) {
    __builtin_amdgcn_global_load_lds(
        (const __attribute__((address_space(1))) void*)g,
        (__attribute__((address_space(3))) void*)l, 16, 0, 0);
}

// ---------------- x f32 -> bf16, padded to M_PAD rows, XOR-swizzled ----------------
__global__ __launch_bounds__(256) void k_cvt_x(const float* __restrict__ x,
                                               short* __restrict__ xs)
{
    int tid = blockIdx.x * 256 + threadIdx.x;  // M_PAD*16 exact
    int row = tid >> 4, ci = tid & 15;
    short o[8];
    if (row < N_NODES) {
        float4 a = *(const float4*)&x[(size_t)row * 128 + ci * 8];
        float4 b = *(const float4*)&x[(size_t)row * 128 + ci * 8 + 4];
        o[0] = f2bf(a.x); o[1] = f2bf(a.y); o[2] = f2bf(a.z); o[3] = f2bf(a.w);
        o[4] = f2bf(b.x); o[5] = f2bf(b.y); o[6] = f2bf(b.z); o[7] = f2bf(b.w);
    } else {
        #pragma unroll
        for (int j = 0; j < 8; ++j) o[j] = 0;
    }
    int cs = ci ^ (row & 7);
    *(int4*)&xs[(size_t)row * 128 + cs * 8] = *(int4*)o;
}

// ---------------- W [K=128][N=128] f32 -> Wt bf16 [n][k], swizzled ----------------
__global__ __launch_bounds__(256) void k_cvt_w(
    const float* __restrict__ Wq, const float* __restrict__ Wk,
    const float* __restrict__ Wv, const float* __restrict__ Wsm,
    short* __restrict__ wt)
{
    int tid = blockIdx.x * 256 + threadIdx.x;  // 8192 exact
    int mat = tid >> 11, n = (tid >> 4) & 127, kg = tid & 15;
    const float* W = (mat == 0) ? Wq : (mat == 1) ? Wk : (mat == 2) ? Wv : Wsm;
    short o[8];
    #pragma unroll
    for (int j = 0; j < 8; ++j) o[j] = f2bf(W[(kg * 8 + j) * 128 + n]);
    int cs = kg ^ (n & 7);
    *(int4*)&wt[mat * 16384 + n * 128 + cs * 8] = *(int4*)o;
}

// ---------------- MFMA GEMM: q,s -> f32; k,v -> fp16 ----------------
__global__ __launch_bounds__(256) void k_mm(
    const short* __restrict__ xs, const short* __restrict__ wt,
    const float* __restrict__ bq, const float* __restrict__ bk,
    const float* __restrict__ bv, const float* __restrict__ bs,
    float* __restrict__ q, __half* __restrict__ kb,
    __half* __restrict__ vb, float* __restrict__ s)
{
    __shared__ __align__(16) char As[32768];
    __shared__ __align__(16) char Bs[32768];
    const int t = threadIdx.x, lane = t & 63, wv = t >> 6;
    const int bm = blockIdx.x >> 2, nt = blockIdx.x & 3;
    const int m0 = bm * 128;

    const char* gA = (const char*)xs + (size_t)m0 * 256;
    const char* gB = (const char*)wt + nt * 32768;
    #pragma unroll
    for (int i = 0; i < 8; ++i) {
        int chunk = wv * 8 + i;
        gload_lds16(gA + chunk * 1024 + lane * 16, As + chunk * 1024);
        gload_lds16(gB + chunk * 1024 + lane * 16, Bs + chunk * 1024);
    }

    const float* Bb = (nt == 0) ? bq : (nt == 1) ? bk : (nt == 2) ? bv : bs;
    const int wm = wv >> 1, wn = wv & 1;
    f32x4 acc[4][4];
    #pragma unroll
    for (int nf = 0; nf < 4; ++nf) {
        float bc = Bb[wn * 64 + nf * 16 + (lane & 15)];
        #pragma unroll
        for (int mf = 0; mf < 4; ++mf) acc[mf][nf] = (f32x4){bc, bc, bc, bc};
    }
    __syncthreads();

    #pragma unroll
    for (int ks = 0; ks < 4; ++ks) {
        bf16x8 af[4], bfr[4];
        const int cbase = ks * 64 + ((lane >> 4) << 4);
        #pragma unroll
        for (int mf = 0; mf < 4; ++mf) {
            int mr = wm * 64 + mf * 16 + (lane & 15);
            af[mf] = *(const bf16x8*)(As + mr * 256 + (cbase ^ ((mr & 7) << 4)));
        }
        #pragma unroll
        for (int nf = 0; nf < 4; ++nf) {
            int nc = wn * 64 + nf * 16 + (lane & 15);
            bfr[nf] = *(const bf16x8*)(Bs + nc * 256 + (cbase ^ ((nc & 7) << 4)));
        }
        #pragma unroll
        for (int mf = 0; mf < 4; ++mf)
            #pragma unroll
            for (int nf = 0; nf < 4; ++nf)
                acc[mf][nf] = __builtin_amdgcn_mfma_f32_16x16x32_bf16(
                    af[mf], bfr[nf], acc[mf][nf], 0, 0, 0);
    }

    const int colbase = wn * 64 + (lane & 15);
    if (nt == 0 || nt == 3) {
        float* O = (nt == 0) ? q : s;
        #pragma unroll
        for (int mf = 0; mf < 4; ++mf) {
            int rowb = m0 + wm * 64 + mf * 16 + ((lane >> 4) << 2);
            #pragma unroll
            for (int nf = 0; nf < 4; ++nf) {
                int col = colbase + nf * 16;
                #pragma unroll
                for (int r = 0; r < 4; ++r) {
                    int node = rowb + r;
                    if (node < N_NODES) O[(size_t)node * 128 + col] = acc[mf][nf][r];
                }
            }
        }
    } else {
        __half* O = (nt == 1) ? kb : vb;
        #pragma unroll
        for (int mf = 0; mf < 4; ++mf) {
            int rowb = m0 + wm * 64 + mf * 16 + ((lane >> 4) << 2);
            #pragma unroll
            for (int nf = 0; nf < 4; ++nf) {
                int col = colbase + nf * 16;
                #pragma unroll
                for (int r = 0; r < 4; ++r) {
                    int node = rowb + r;
                    if (node < N_NODES)
                        O[(size_t)node * 128 + col] = __float2half_rn(acc[mf][nf][r]);
                }
            }
        }
    }
}

// ---------------- CSR build: histogram / 3-phase parallel scan / scatter ----------------
__global__ __launch_bounds__(256) void k_hist(const int* __restrict__ dst,
                                              int* __restrict__ deg)
{
    int e = blockIdx.x * 256 + threadIdx.x;  // E exact
    atomicAdd(&deg[dst[e]], 1);
}

// Phase 1: per-block sums of 256 degrees
__global__ __launch_bounds__(256) void k_scan1(const int* __restrict__ deg,
                                               int* __restrict__ part)
{
    const int t = threadIdx.x;
    int idx = blockIdx.x * 256 + t;
    int v = (idx < N_NODES) ? deg[idx] : 0;
    #pragma unroll
    for (int o = 1; o < 64; o <<= 1) v += __shfl_xor(v, o);
    __shared__ int wsum[4];
    if ((t & 63) == 0) wsum[t >> 6] = v;
    __syncthreads();
    if (t == 0) part[blockIdx.x] = wsum[0] + wsum[1] + wsum[2] + wsum[3];
}

// Phase 2: exclusive scan of the 196 partials (single small block)
__global__ __launch_bounds__(256) void k_scan2(int* __restrict__ part)
{
    __shared__ int buf[256];
    const int t = threadIdx.x;
    int v = (t < SCAN_BLOCKS) ? part[t] : 0;
    buf[t] = v;
    __syncthreads();
    for (int o = 1; o < 256; o <<= 1) {
        int tmp = (t >= o) ? buf[t - o] : 0;
        __syncthreads();
        buf[t] += tmp;
        __syncthreads();
    }
    if (t < SCAN_BLOCKS) part[t] = buf[t] - v;  // exclusive
}

// Phase 3: intra-block exclusive scan + block base -> offs, cursor
__global__ __launch_bounds__(256) void k_scan3(const int* __restrict__ deg,
                                               const int* __restrict__ part,
                                               int* __restrict__ offs,
                                               int* __restrict__ cursor)
{
    const int t = threadIdx.x;
    const int idx = blockIdx.x * 256 + t;
    const int lane = t & 63, w = t >> 6;
    int v = (idx < N_NODES) ? deg[idx] : 0;
    int inc = v;
    #pragma unroll
    for (int o = 1; o < 64; o <<= 1) {
        int nb = __shfl_up(inc, o);
        if (lane >= o) inc += nb;
    }
    __shared__ int wsum[4];
    if (lane == 63) wsum[w] = inc;
    __syncthreads();
    int wbase = 0;
    #pragma unroll
    for (int i = 0; i < 4; ++i) if (i < w) wbase += wsum[i];
    int excl = part[blockIdx.x] + wbase + inc - v;
    if (idx < N_NODES) {
        offs[idx] = excl;
        cursor[idx] = excl;
    }
    if (idx == 0) offs[N_NODES] = N_EDGES;
}

__global__ __launch_bounds__(256) void k_scatter(
    const int* __restrict__ src, const int* __restrict__ dst,
    int* __restrict__ cursor, int* __restrict__ csr_src, int* __restrict__ csr_eid)
{
    int e = blockIdx.x * 256 + threadIdx.x;  // E exact
    int d = dst[e];
    int pos = atomicAdd(&cursor[d], 1);
    csr_src[pos] = src[e];
    csr_eid[pos] = e;
}

// ---------------- fused: logits + exp + denom + aggregate + skip ----------------
// One 64-lane wave per dst node; lane l owns channels (2l, 2l+1); head = l>>4.
// NO contended atomics here (round-4 lesson: 100K same-line atomics cost ~250us).
__global__ __launch_bounds__(256) void k_fused(
    const float* __restrict__ q, const __half2* __restrict__ kb,
    const __half2* __restrict__ vb, const float* __restrict__ s,
    const int* __restrict__ offs, const int* __restrict__ csr_src,
    const int* __restrict__ csr_eid,
    float* __restrict__ exbuf, float* __restrict__ denom,
    float* __restrict__ outb)
{
    const int t = threadIdx.x;
    const int lane = t & 63;
    const int n = blockIdx.x * 4 + (t >> 6);  // grid*4 == N exact
    const int begin = offs[n], end = offs[n + 1];
    const float2 qv = *(const float2*)&q[(size_t)n * 128 + lane * 2];
    const int h = lane >> 4;
    float acc0 = 0.f, acc1 = 0.f, dsum = 0.f;
    int i = begin;
    // unroll x4: issue all 8 index loads, then all 8 row loads, then consume
    for (; i + 4 <= end; i += 4) {
        int sn[4], eid[4];
        #pragma unroll
        for (int u = 0; u < 4; ++u) { sn[u] = csr_src[i + u]; eid[u] = csr_eid[i + u]; }
        __half2 kh[4], vh[4];
        #pragma unroll
        for (int u = 0; u < 4; ++u) kh[u] = kb[(size_t)sn[u] * 64 + lane];
        #pragma unroll
        for (int u = 0; u < 4; ++u) vh[u] = vb[(size_t)sn[u] * 64 + lane];
        float p[4];
        #pragma unroll
        for (int u = 0; u < 4; ++u) {
            float2 kf = __half22float2(kh[u]);
            p[u] = qv.x * kf.x + qv.y * kf.y;
        }
        #pragma unroll
        for (int u = 0; u < 4; ++u) p[u] += __shfl_xor(p[u], 1);
        #pragma unroll
        for (int u = 0; u < 4; ++u) p[u] += __shfl_xor(p[u], 2);
        #pragma unroll
        for (int u = 0; u < 4; ++u) p[u] += __shfl_xor(p[u], 4);
        #pragma unroll
        for (int u = 0; u < 4; ++u) p[u] += __shfl_xor(p[u], 8);
        #pragma unroll
        for (int u = 0; u < 4; ++u) {
            float ex = __expf(p[u] * RSQRT_D);
            dsum += ex;
            float2 vf = __half22float2(vh[u]);
            acc0 += ex * vf.x;
            acc1 += ex * vf.y;
            if ((lane & 15) == 0) exbuf[eid[u] * 4 + h] = ex;
        }
    }
    for (; i < end; ++i) {
        const int sn0 = csr_src[i];
        const int e0  = csr_eid[i];
        const __half2 kh0 = kb[(size_t)sn0 * 64 + lane];
        const __half2 vh0 = vb[(size_t)sn0 * 64 + lane];
        const float2 k0 = __half22float2(kh0);
        float p0 = qv.x * k0.x + qv.y * k0.y;
        p0 += __shfl_xor(p0, 1);
        p0 += __shfl_xor(p0, 2);
        p0 += __shfl_xor(p0, 4);
        p0 += __shfl_xor(p0, 8);
        const float ex0 = __expf(p0 * RSQRT_D);
        dsum += ex0;
        const float2 v0 = __half22float2(vh0);
        acc0 += ex0 * v0.x;
        acc1 += ex0 * v0.y;
        if ((lane & 15) == 0) exbuf[e0 * 4 + h] = ex0;
    }
    if ((lane & 15) == 0) denom[n * 4 + h] = dsum;
    const float rdn = 1.f / (dsum + 1e-16f);
    const float2 sv = *(const float2*)&s[(size_t)n * 128 + lane * 2];
    float2 o = make_float2(acc0 * rdn + sv.x, acc1 * rdn + sv.y);
    *(float2*)&outb[(size_t)n * 128 + lane * 2] = o;
}

// ---------------- normalize attn in place ----------------
__global__ __launch_bounds__(256) void k_norm(
    float* __restrict__ attn, const float* __restrict__ denom,
    const int* __restrict__ dst)
{
    int idx = blockIdx.x * 256 + threadIdx.x;  // E*4 exact
    int e = idx >> 2, h = idx & 3;
    attn[idx] = attn[idx] / (denom[dst[e] * 4 + h] + 1e-16f);
}

// ---------------- per-graph sum & count (run-length -> few atomics) ----------------
__global__ __launch_bounds__(256) void k_sum(
    const float* __restrict__ out, const int* __restrict__ batch,
    float* __restrict__ gsum, int* __restrict__ gcnt)
{
    __shared__ float nsum[32];
    __shared__ int   ngr[32];
    const int t = threadIdx.x;
    const int nl = t >> 3, part = t & 7;
    const int n = blockIdx.x * 32 + nl;
    float lsum = 0.f;
    if (n < N_NODES) {
        size_t base = (size_t)n * 128 + part * 16;
        #pragma unroll
        for (int i = 0; i < 4; ++i) {
            float4 o = *(const float4*)&out[base + i * 4];
            lsum += o.x + o.y + o.z + o.w;
        }
    }
    lsum += __shfl_xor(lsum, 1);
    lsum += __shfl_xor(lsum, 2);
    lsum += __shfl_xor(lsum, 4);
    if (part == 0) { nsum[nl] = lsum; ngr[nl] = (n < N_NODES) ? batch[n] : -1; }
    __syncthreads();
    if (t == 0) {
        float acc = 0.f; int cg = ngr[0], cnt = 0;
        for (int i = 0; i < 32; ++i) {
            int g = ngr[i];
            if (g != cg) {
                if (cg >= 0) { atomicAdd(&gsum[cg], acc); atomicAdd(&gcnt[cg], cnt); }
                acc = 0.f; cnt = 0; cg = g;
            }
            acc += nsum[i]; ++cnt;
        }
        if (cg >= 0) { atomicAdd(&gsum[cg], acc); atomicAdd(&gcnt[cg], cnt); }
    }
}

// ---------------- per-graph centered sum of squares ----------------
__global__ __launch_bounds__(256) void k_var(
    const float* __restrict__ out, const int* __restrict__ batch,
    const float* __restrict__ gsum, const int* __restrict__ gcnt,
    float* __restrict__ gvar)
{
    __shared__ float nsum[32];
    __shared__ int   ngr[32];
    const int t = threadIdx.x;
    const int nl = t >> 3, part = t & 7;
    const int n = blockIdx.x * 32 + nl;
    float lsum = 0.f;
    if (n < N_NODES) {
        int g = batch[n];
        float mean = gsum[g] / (fmaxf((float)gcnt[g], 1.f) * 128.f);
        size_t base = (size_t)n * 128 + part * 16;
        #pragma unroll
        for (int i = 0; i < 4; ++i) {
            float4 o = *(const float4*)&out[base + i * 4];
            float dx = o.x - mean, dy = o.y - mean, dz = o.z - mean, dw = o.w - mean;
            lsum += dx * dx + dy * dy + dz * dz + dw * dw;
        }
    }
    lsum += __shfl_xor(lsum, 1);
    lsum += __shfl_xor(lsum, 2);
    lsum += __shfl_xor(lsum, 4);
    if (part == 0) { nsum[nl] = lsum; ngr[nl] = (n < N_NODES) ? batch[n] : -1; }
    __syncthreads();
    if (t == 0) {
        float acc = 0.f; int cg = ngr[0];
        for (int i = 0; i < 32; ++i) {
            int g = ngr[i];
            if (g != cg) {
                if (cg >= 0) atomicAdd(&gvar[cg], acc);
                acc = 0.f; cg = g;
            }
            acc += nsum[i];
        }
        if (cg >= 0) atomicAdd(&gvar[cg], acc);
    }
}

// ---------------- LayerNorm affine + LeakyReLU (in-place) ----------------
__global__ __launch_bounds__(256) void k_final(
    const float* __restrict__ out, const int* __restrict__ batch,
    const float* __restrict__ gsum, const float* __restrict__ gvar,
    const int* __restrict__ gcnt,
    const float* __restrict__ lnw, const float* __restrict__ lnb,
    float* __restrict__ y)
{
    int idx = blockIdx.x * 256 + threadIdx.x;  // N*128 exact
    int n = idx >> 7, c = idx & 127;
    int g = batch[n];
    float norm = fmaxf((float)gcnt[g], 1.f) * 128.f;
    float mean = gsum[g] / norm;
    float var  = gvar[g] / norm;
    float inv  = rsqrtf(var + 1e-5f);
    float val  = (out[idx] - mean) * inv * lnw[c] + lnb[c];
    y[idx] = val > 0.f ? val : 0.01f * val;
}

extern "C" void kernel_launch(void* const* d_in, const int* in_sizes, int n_in,
                              void* d_out, int out_size, void* d_ws, size_t ws_size,
                              hipStream_t stream)
{
    (void)in_sizes; (void)n_in; (void)out_size; (void)ws_size;
    const float* x    = (const float*)d_in[0];
    const int*   ei   = (const int*)  d_in[1];
    const int*   batch= (const int*)  d_in[2];
    const float* Wq   = (const float*)d_in[3];
    const float* bq   = (const float*)d_in[4];
    const float* Wk   = (const float*)d_in[5];
    const float* bk   = (const float*)d_in[6];
    const float* Wv   = (const float*)d_in[7];
    const float* bv   = (const float*)d_in[8];
    const float* Wsm  = (const float*)d_in[9];
    const float* bs   = (const float*)d_in[10];
    const float* lnw  = (const float*)d_in[11];
    const float* lnb  = (const float*)d_in[12];

    float* outp = (float*)d_out;
    float* ws   = (float*)d_ws;

    const int* srcI = ei;
    const int* dstI = ei + N_EDGES;

    float*  q       = ws + OFF_Q;
    __half* kb      = (__half*)(ws + OFF_K);
    __half* vb      = (__half*)(ws + OFF_V);
    float*  s       = ws + OFF_S;
    float*  denom   = ws + OFF_DENOM;
    short*  wt      = (short*)(ws + OFF_DENOM);  // dead before k_fused writes denom
    float*  gsum    = ws + OFF_GSUM;
    float*  gvar    = ws + OFF_GVAR;
    int*    gcnt    = (int*)(ws + OFF_GCNT);
    int*    deg     = (int*)(ws + OFF_DEG);
    int*    offs    = (int*)(ws + OFF_OFFS);
    int*    cursor  = (int*)(ws + OFF_CURSOR);
    int*    csr_src = (int*)(ws + OFF_CSRSRC);
    int*    csr_eid = (int*)(ws + OFF_CSREID);
    int*    partArr = (int*)(ws + OFF_PART);

    float* outb  = outp;                  // y region: x_swz first, then pre-LN out
    short* x_swz = (short*)outp;          // 12.8 MB, dead once k_mm finishes
    float* attn  = outp + Y_SIZE;

    // zero gsum/gvar/gcnt + deg
    hipMemsetAsync(gsum, 0, (size_t)(192 + N_NODES) * sizeof(float), stream);

    k_cvt_w<<<32, 256, 0, stream>>>(Wq, Wk, Wv, Wsm, wt);
    k_cvt_x<<<(M_PAD * 16) / 256, 256, 0, stream>>>(x, x_swz);
    k_mm<<<(M_PAD / 128) * 4, 256, 0, stream>>>(x_swz, wt, bq, bk, bv, bs,
                                                q, kb, vb, s);

    k_hist<<<N_EDGES / 256, 256, 0, stream>>>(dstI, deg);
    k_scan1<<<SCAN_BLOCKS, 256, 0, stream>>>(deg, partArr);
    k_scan2<<<1, 256, 0, stream>>>(partArr);
    k_scan3<<<SCAN_BLOCKS, 256, 0, stream>>>(deg, partArr, offs, cursor);
    k_scatter<<<N_EDGES / 256, 256, 0, stream>>>(srcI, dstI, cursor, csr_src, csr_eid);
    k_fused<<<N_NODES / 4, 256, 0, stream>>>(q, (const __half2*)kb, (const __half2*)vb,
                                             s, offs, csr_src, csr_eid,
                                             attn, denom, outb);
    k_norm<<<(N_EDGES * 4) / 256, 256, 0, stream>>>(attn, denom, dstI);
    k_sum<<<(N_NODES + 31) / 32, 256, 0, stream>>>(outb, batch, gsum, gcnt);
    k_var<<<(N_NODES + 31) / 32, 256, 0, stream>>>(outb, batch, gsum, gcnt, gvar);
    k_final<<<Y_SIZE / 256, 256, 0, stream>>>(outb, batch, gsum, gvar, gcnt,
                                              lnw, lnb, outp);
}

// Round 7
// 266.323 us; speedup vs baseline: 2.7545x; 1.0237x over previous
//
#include <hip/hip_runtime.h>
#include <hip/hip_fp16.h>

constexpr int N_NODES = 50000;
constexpr int N_EDGES = 800000;
constexpr int HIDDEN  = 128;
constexpr float RSQRT_D = 0.17677669529663687f;  // 1/sqrt(32)
constexpr int Y_SIZE = N_NODES * HIDDEN;         // 6,400,000
constexpr int M_PAD  = 50048;                    // 391 * 128
constexpr int SCAN_BLOCKS = 196;                 // 196*256 = 50176 >= N_NODES
constexpr int XCVT_BLOCKS = (M_PAD * 16) / 256;  // 3128

// ---- ws layout (float offsets) ----
constexpr size_t OFF_Q      = 0;         // fp16 qb (12.8 MB of 25.6 slot)
constexpr size_t OFF_K      = 6400000;   // fp16 kb
constexpr size_t OFF_V      = 12800000;  // fp16 vb
constexpr size_t OFF_S      = 19200000;  // f32 s
constexpr size_t OFF_DENOM  = 25600000;  // N*4 floats; ALSO hosts Wt_swz (dead before k_fused)
constexpr size_t OFF_GSUM   = 25800000;  // 64
constexpr size_t OFF_GSQ    = 25800064;  // 64
constexpr size_t OFF_GCNT   = 25800128;  // 64 ints
constexpr size_t OFF_DEG    = 25800192;  // 50000 ints
constexpr size_t OFF_OFFS   = 25850192;  // 50001 ints
constexpr size_t OFF_CURSOR = 25900224;  // 50000 ints
constexpr size_t OFF_CSR    = 25950224;  // 800000 int2 (packed src,eid)
constexpr size_t OFF_PART   = 27550224;  // 196 ints (scan partials)

typedef __attribute__((ext_vector_type(8))) short bf16x8;
typedef __attribute__((ext_vector_type(4))) float f32x4;

__device__ __forceinline__ short f2bf(float f) {  // RNE f32 -> bf16 bits
    unsigned u = __float_as_uint(f);
    unsigned r = (u + 0x7fff + ((u >> 16) & 1)) >> 16;
    return (short)r;
}

__device__ __forceinline__ void gload_lds16(const void* g, void* l) {
    __builtin_amdgcn_global_load_lds(
        (const __attribute__((address_space(1))) void*)g,
        (__attribute__((address_space(3))) void*)l, 16, 0, 0);
}

// ---------------- combined cvt: x -> bf16 swizzled; W -> Wt bf16 swizzled ----------------
__global__ __launch_bounds__(256) void k_cvt(
    const float* __restrict__ x,
    const float* __restrict__ Wq, const float* __restrict__ Wk,
    const float* __restrict__ Wv, const float* __restrict__ Wsm,
    short* __restrict__ xs, short* __restrict__ wt)
{
    int b = blockIdx.x;
    if (b < XCVT_BLOCKS) {
        int tid = b * 256 + threadIdx.x;  // M_PAD*16 exact
        int row = tid >> 4, ci = tid & 15;
        short o[8];
        if (row < N_NODES) {
            float4 a = *(const float4*)&x[(size_t)row * 128 + ci * 8];
            float4 bb = *(const float4*)&x[(size_t)row * 128 + ci * 8 + 4];
            o[0] = f2bf(a.x); o[1] = f2bf(a.y); o[2] = f2bf(a.z); o[3] = f2bf(a.w);
            o[4] = f2bf(bb.x); o[5] = f2bf(bb.y); o[6] = f2bf(bb.z); o[7] = f2bf(bb.w);
        } else {
            #pragma unroll
            for (int j = 0; j < 8; ++j) o[j] = 0;
        }
        int cs = ci ^ (row & 7);
        *(int4*)&xs[(size_t)row * 128 + cs * 8] = *(int4*)o;
    } else {
        int tid = (b - XCVT_BLOCKS) * 256 + threadIdx.x;  // 8192 exact
        int mat = tid >> 11, n = (tid >> 4) & 127, kg = tid & 15;
        const float* W = (mat == 0) ? Wq : (mat == 1) ? Wk : (mat == 2) ? Wv : Wsm;
        short o[8];
        #pragma unroll
        for (int j = 0; j < 8; ++j) o[j] = f2bf(W[(kg * 8 + j) * 128 + n]);
        int cs = kg ^ (n & 7);
        *(int4*)&wt[mat * 16384 + n * 128 + cs * 8] = *(int4*)o;
    }
}

// ---------------- MFMA GEMM, single dispatch: all 4 mats per block ----------------
// Block: 256 thr = 4 waves (2x2), 128x128 tile. A staged once, A-frags in regs;
// B re-staged per mat. q,k,v -> fp16; s -> f32.
__global__ __launch_bounds__(256) void k_mm(
    const short* __restrict__ xs, const short* __restrict__ wt,
    const float* __restrict__ bq, const float* __restrict__ bk,
    const float* __restrict__ bv, const float* __restrict__ bs,
    __half* __restrict__ q, __half* __restrict__ kb,
    __half* __restrict__ vb, float* __restrict__ s)
{
    __shared__ __align__(16) char As[32768];
    __shared__ __align__(16) char Bs[32768];
    const int t = threadIdx.x, lane = t & 63, wv = t >> 6;
    const int m0 = blockIdx.x * 128;
    const int wm = wv >> 1, wn = wv & 1;

    const char* gA = (const char*)xs + (size_t)m0 * 256;
    #pragma unroll
    for (int i = 0; i < 8; ++i) {
        int chunk = wv * 8 + i;
        gload_lds16(gA + chunk * 1024 + lane * 16, As + chunk * 1024);
        gload_lds16((const char*)wt + chunk * 1024 + lane * 16, Bs + chunk * 1024);
    }
    __syncthreads();

    // A fragments once (same for all mats)
    bf16x8 af[4][4];  // [ks][mf]
    #pragma unroll
    for (int ks = 0; ks < 4; ++ks) {
        const int cbase = ks * 64 + ((lane >> 4) << 4);
        #pragma unroll
        for (int mf = 0; mf < 4; ++mf) {
            int mr = wm * 64 + mf * 16 + (lane & 15);
            af[ks][mf] = *(const bf16x8*)(As + mr * 256 + (cbase ^ ((mr & 7) << 4)));
        }
    }

    const float* Bbs[4] = {bq, bk, bv, bs};
    #pragma unroll
    for (int mat = 0; mat < 4; ++mat) {
        f32x4 acc[4][4];
        #pragma unroll
        for (int nf = 0; nf < 4; ++nf) {
            float bc = Bbs[mat][wn * 64 + nf * 16 + (lane & 15)];
            #pragma unroll
            for (int mf = 0; mf < 4; ++mf) acc[mf][nf] = (f32x4){bc, bc, bc, bc};
        }
        #pragma unroll
        for (int ks = 0; ks < 4; ++ks) {
            bf16x8 bfr[4];
            const int cbase = ks * 64 + ((lane >> 4) << 4);
            #pragma unroll
            for (int nf = 0; nf < 4; ++nf) {
                int nc = wn * 64 + nf * 16 + (lane & 15);
                bfr[nf] = *(const bf16x8*)(Bs + nc * 256 + (cbase ^ ((nc & 7) << 4)));
            }
            #pragma unroll
            for (int mf = 0; mf < 4; ++mf)
                #pragma unroll
                for (int nf = 0; nf < 4; ++nf)
                    acc[mf][nf] = __builtin_amdgcn_mfma_f32_16x16x32_bf16(
                        af[ks][mf], bfr[nf], acc[mf][nf], 0, 0, 0);
        }
        __syncthreads();  // all waves done reading Bs
        if (mat < 3) {    // stage next mat's B while we write out
            const char* gB = (const char*)wt + (mat + 1) * 32768;
            #pragma unroll
            for (int i = 0; i < 8; ++i) {
                int chunk = wv * 8 + i;
                gload_lds16(gB + chunk * 1024 + lane * 16, Bs + chunk * 1024);
            }
        }
        const int colbase = wn * 64 + (lane & 15);
        if (mat == 3) {
            #pragma unroll
            for (int mf = 0; mf < 4; ++mf) {
                int rowb = m0 + wm * 64 + mf * 16 + ((lane >> 4) << 2);
                #pragma unroll
                for (int nf = 0; nf < 4; ++nf) {
                    int col = colbase + nf * 16;
                    #pragma unroll
                    for (int r = 0; r < 4; ++r) {
                        int node = rowb + r;
                        if (node < N_NODES) s[(size_t)node * 128 + col] = acc[mf][nf][r];
                    }
                }
            }
        } else {
            __half* O = (mat == 0) ? q : (mat == 1) ? kb : vb;
            #pragma unroll
            for (int mf = 0; mf < 4; ++mf) {
                int rowb = m0 + wm * 64 + mf * 16 + ((lane >> 4) << 2);
                #pragma unroll
                for (int nf = 0; nf < 4; ++nf) {
                    int col = colbase + nf * 16;
                    #pragma unroll
                    for (int r = 0; r < 4; ++r) {
                        int node = rowb + r;
                        if (node < N_NODES)
                            O[(size_t)node * 128 + col] = __float2half_rn(acc[mf][nf][r]);
                    }
                }
            }
        }
        __syncthreads();  // staged Bs complete before next mat's reads
    }
}

// ---------------- CSR build: histogram / 3-phase parallel scan / scatter ----------------
__global__ __launch_bounds__(256) void k_hist(const int* __restrict__ dst,
                                              int* __restrict__ deg)
{
    int e = blockIdx.x * 256 + threadIdx.x;  // E exact
    atomicAdd(&deg[dst[e]], 1);
}

__global__ __launch_bounds__(256) void k_scan1(const int* __restrict__ deg,
                                               int* __restrict__ part)
{
    const int t = threadIdx.x;
    int idx = blockIdx.x * 256 + t;
    int v = (idx < N_NODES) ? deg[idx] : 0;
    #pragma unroll
    for (int o = 1; o < 64; o <<= 1) v += __shfl_xor(v, o);
    __shared__ int wsum[4];
    if ((t & 63) == 0) wsum[t >> 6] = v;
    __syncthreads();
    if (t == 0) part[blockIdx.x] = wsum[0] + wsum[1] + wsum[2] + wsum[3];
}

__global__ __launch_bounds__(256) void k_scan2(int* __restrict__ part)
{
    __shared__ int buf[256];
    const int t = threadIdx.x;
    int v = (t < SCAN_BLOCKS) ? part[t] : 0;
    buf[t] = v;
    __syncthreads();
    for (int o = 1; o < 256; o <<= 1) {
        int tmp = (t >= o) ? buf[t - o] : 0;
        __syncthreads();
        buf[t] += tmp;
        __syncthreads();
    }
    if (t < SCAN_BLOCKS) part[t] = buf[t] - v;  // exclusive
}

__global__ __launch_bounds__(256) void k_scan3(const int* __restrict__ deg,
                                               const int* __restrict__ part,
                                               int* __restrict__ offs,
                                               int* __restrict__ cursor)
{
    const int t = threadIdx.x;
    const int idx = blockIdx.x * 256 + t;
    const int lane = t & 63, w = t >> 6;
    int v = (idx < N_NODES) ? deg[idx] : 0;
    int inc = v;
    #pragma unroll
    for (int o = 1; o < 64; o <<= 1) {
        int nb = __shfl_up(inc, o);
        if (lane >= o) inc += nb;
    }
    __shared__ int wsum[4];
    if (lane == 63) wsum[w] = inc;
    __syncthreads();
    int wbase = 0;
    #pragma unroll
    for (int i = 0; i < 4; ++i) if (i < w) wbase += wsum[i];
    int excl = part[blockIdx.x] + wbase + inc - v;
    if (idx < N_NODES) {
        offs[idx] = excl;
        cursor[idx] = excl;
    }
    if (idx == 0) offs[N_NODES] = N_EDGES;
}

__global__ __launch_bounds__(256) void k_scatter(
    const int* __restrict__ src, const int* __restrict__ dst,
    int* __restrict__ cursor, int2* __restrict__ csr)
{
    int e = blockIdx.x * 256 + threadIdx.x;  // E exact
    int d = dst[e];
    int pos = atomicAdd(&cursor[d], 1);
    csr[pos] = make_int2(src[e], e);
}

// ---------------- fused: logits + exp + denom + aggregate + skip ----------------
// One 64-lane wave per dst node; lane l owns channels (2l, 2l+1); head = l>>4.
// NO contended atomics (round-4 lesson). Unroll 8 for MLP (round-6: latency-mixed).
__global__ __launch_bounds__(256) void k_fused(
    const __half2* __restrict__ qb, const __half2* __restrict__ kb,
    const __half2* __restrict__ vb, const float* __restrict__ s,
    const int* __restrict__ offs, const int2* __restrict__ csr,
    float* __restrict__ exbuf, float* __restrict__ denom,
    float* __restrict__ outb)
{
    const int t = threadIdx.x;
    const int lane = t & 63;
    const int n = blockIdx.x * 4 + (t >> 6);  // grid*4 == N exact
    const int begin = offs[n], end = offs[n + 1];
    const float2 qv = __half22float2(qb[(size_t)n * 64 + lane]);
    const float2 sv = *(const float2*)&s[(size_t)n * 128 + lane * 2];
    const int h = lane >> 4;
    float acc0 = 0.f, acc1 = 0.f, dsum = 0.f;
    int i = begin;
    for (; i + 8 <= end; i += 8) {
        int2 c[8];
        #pragma unroll
        for (int u = 0; u < 8; ++u) c[u] = csr[i + u];
        __half2 kh[8], vh[8];
        #pragma unroll
        for (int u = 0; u < 8; ++u) kh[u] = kb[(size_t)c[u].x * 64 + lane];
        #pragma unroll
        for (int u = 0; u < 8; ++u) vh[u] = vb[(size_t)c[u].x * 64 + lane];
        float p[8];
        #pragma unroll
        for (int u = 0; u < 8; ++u) {
            float2 kf = __half22float2(kh[u]);
            p[u] = qv.x * kf.x + qv.y * kf.y;
        }
        #pragma unroll
        for (int u = 0; u < 8; ++u) p[u] += __shfl_xor(p[u], 1);
        #pragma unroll
        for (int u = 0; u < 8; ++u) p[u] += __shfl_xor(p[u], 2);
        #pragma unroll
        for (int u = 0; u < 8; ++u) p[u] += __shfl_xor(p[u], 4);
        #pragma unroll
        for (int u = 0; u < 8; ++u) p[u] += __shfl_xor(p[u], 8);
        #pragma unroll
        for (int u = 0; u < 8; ++u) {
            float ex = __expf(p[u] * RSQRT_D);
            dsum += ex;
            float2 vf = __half22float2(vh[u]);
            acc0 += ex * vf.x;
            acc1 += ex * vf.y;
            if ((lane & 15) == 0) exbuf[c[u].y * 4 + h] = ex;
        }
    }
    for (; i < end; ++i) {
        const int2 c0 = csr[i];
        const __half2 kh0 = kb[(size_t)c0.x * 64 + lane];
        const __half2 vh0 = vb[(size_t)c0.x * 64 + lane];
        const float2 k0 = __half22float2(kh0);
        float p0 = qv.x * k0.x + qv.y * k0.y;
        p0 += __shfl_xor(p0, 1);
        p0 += __shfl_xor(p0, 2);
        p0 += __shfl_xor(p0, 4);
        p0 += __shfl_xor(p0, 8);
        const float ex0 = __expf(p0 * RSQRT_D);
        dsum += ex0;
        const float2 v0 = __half22float2(vh0);
        acc0 += ex0 * v0.x;
        acc1 += ex0 * v0.y;
        if ((lane & 15) == 0) exbuf[c0.y * 4 + h] = ex0;
    }
    if ((lane & 15) == 0) denom[n * 4 + h] = dsum;
    const float rdn = 1.f / (dsum + 1e-16f);
    float2 o = make_float2(acc0 * rdn + sv.x, acc1 * rdn + sv.y);
    *(float2*)&outb[(size_t)n * 128 + lane * 2] = o;
}

// ---------------- normalize attn in place ----------------
__global__ __launch_bounds__(256) void k_norm(
    float* __restrict__ attn, const float* __restrict__ denom,
    const int* __restrict__ dst)
{
    int idx = blockIdx.x * 256 + threadIdx.x;  // E*4 exact
    int e = idx >> 2, h = idx & 3;
    attn[idx] = attn[idx] / (denom[dst[e] * 4 + h] + 1e-16f);
}

// ---------------- per-graph sum + sumsq + count, one pass ----------------
__global__ __launch_bounds__(256) void k_stats(
    const float* __restrict__ out, const int* __restrict__ batch,
    float* __restrict__ gsum, float* __restrict__ gsq, int* __restrict__ gcnt)
{
    __shared__ float nsum[32], nsq[32];
    __shared__ int   ngr[32];
    const int t = threadIdx.x;
    const int nl = t >> 3, part = t & 7;
    const int n = blockIdx.x * 32 + nl;
    float lsum = 0.f, lsq = 0.f;
    if (n < N_NODES) {
        size_t base = (size_t)n * 128 + part * 16;
        #pragma unroll
        for (int i = 0; i < 4; ++i) {
            float4 o = *(const float4*)&out[base + i * 4];
            lsum += o.x + o.y + o.z + o.w;
            lsq  += o.x * o.x + o.y * o.y + o.z * o.z + o.w * o.w;
        }
    }
    #pragma unroll
    for (int o = 1; o < 8; o <<= 1) {
        lsum += __shfl_xor(lsum, o);
        lsq  += __shfl_xor(lsq, o);
    }
    if (part == 0) { nsum[nl] = lsum; nsq[nl] = lsq; ngr[nl] = (n < N_NODES) ? batch[n] : -1; }
    __syncthreads();
    if (t == 0) {
        float acc = 0.f, accq = 0.f; int cg = ngr[0], cnt = 0;
        for (int i = 0; i < 32; ++i) {
            int g = ngr[i];
            if (g != cg) {
                if (cg >= 0) { atomicAdd(&gsum[cg], acc); atomicAdd(&gsq[cg], accq);
                               atomicAdd(&gcnt[cg], cnt); }
                acc = 0.f; accq = 0.f; cnt = 0; cg = g;
            }
            acc += nsum[i]; accq += nsq[i]; ++cnt;
        }
        if (cg >= 0) { atomicAdd(&gsum[cg], acc); atomicAdd(&gsq[cg], accq);
                       atomicAdd(&gcnt[cg], cnt); }
    }
}

// ---------------- LayerNorm affine + LeakyReLU (in-place) ----------------
__global__ __launch_bounds__(256) void k_final(
    const float* __restrict__ out, const int* __restrict__ batch,
    const float* __restrict__ gsum, const float* __restrict__ gsq,
    const int* __restrict__ gcnt,
    const float* __restrict__ lnw, const float* __restrict__ lnb,
    float* __restrict__ y)
{
    int idx = blockIdx.x * 256 + threadIdx.x;  // N*128 exact
    int n = idx >> 7, c = idx & 127;
    int g = batch[n];
    float norm = fmaxf((float)gcnt[g], 1.f) * 128.f;
    float mean = gsum[g] / norm;
    float var  = gsq[g] / norm - mean * mean;
    float inv  = rsqrtf(var + 1e-5f);
    float val  = (out[idx] - mean) * inv * lnw[c] + lnb[c];
    y[idx] = val > 0.f ? val : 0.01f * val;
}

extern "C" void kernel_launch(void* const* d_in, const int* in_sizes, int n_in,
                              void* d_out, int out_size, void* d_ws, size_t ws_size,
                              hipStream_t stream)
{
    (void)in_sizes; (void)n_in; (void)out_size; (void)ws_size;
    const float* x    = (const float*)d_in[0];
    const int*   ei   = (const int*)  d_in[1];
    const int*   batch= (const int*)  d_in[2];
    const float* Wq   = (const float*)d_in[3];
    const float* bq   = (const float*)d_in[4];
    const float* Wk   = (const float*)d_in[5];
    const float* bk   = (const float*)d_in[6];
    const float* Wv   = (const float*)d_in[7];
    const float* bv   = (const float*)d_in[8];
    const float* Wsm  = (const float*)d_in[9];
    const float* bs   = (const float*)d_in[10];
    const float* lnw  = (const float*)d_in[11];
    const float* lnb  = (const float*)d_in[12];

    float* outp = (float*)d_out;
    float* ws   = (float*)d_ws;

    const int* srcI = ei;
    const int* dstI = ei + N_EDGES;

    __half* qb      = (__half*)(ws + OFF_Q);
    __half* kb      = (__half*)(ws + OFF_K);
    __half* vb      = (__half*)(ws + OFF_V);
    float*  s       = ws + OFF_S;
    float*  denom   = ws + OFF_DENOM;
    short*  wt      = (short*)(ws + OFF_DENOM);  // dead before k_fused writes denom
    float*  gsum    = ws + OFF_GSUM;
    float*  gsq     = ws + OFF_GSQ;
    int*    gcnt    = (int*)(ws + OFF_GCNT);
    int*    deg     = (int*)(ws + OFF_DEG);
    int*    offs    = (int*)(ws + OFF_OFFS);
    int*    cursor  = (int*)(ws + OFF_CURSOR);
    int2*   csr     = (int2*)(ws + OFF_CSR);
    int*    partArr = (int*)(ws + OFF_PART);

    float* outb  = outp;                  // y region: x_swz first, then pre-LN out
    short* x_swz = (short*)outp;          // 12.8 MB, dead once k_mm finishes
    float* attn  = outp + Y_SIZE;

    // zero gsum/gsq/gcnt + deg (contiguous)
    hipMemsetAsync(gsum, 0, (size_t)(192 + N_NODES) * sizeof(float), stream);

    k_cvt<<<XCVT_BLOCKS + 32, 256, 0, stream>>>(x, Wq, Wk, Wv, Wsm, x_swz, wt);
    k_mm<<<M_PAD / 128, 256, 0, stream>>>(x_swz, wt, bq, bk, bv, bs, qb, kb, vb, s);

    k_hist<<<N_EDGES / 256, 256, 0, stream>>>(dstI, deg);
    k_scan1<<<SCAN_BLOCKS, 256, 0, stream>>>(deg, partArr);
    k_scan2<<<1, 256, 0, stream>>>(partArr);
    k_scan3<<<SCAN_BLOCKS, 256, 0, stream>>>(deg, partArr, offs, cursor);
    k_scatter<<<N_EDGES / 256, 256, 0, stream>>>(srcI, dstI, cursor, csr);
    k_fused<<<N_NODES / 4, 256, 0, stream>>>((const __half2*)qb, (const __half2*)kb,
                                             (const __half2*)vb, s, offs, csr,
                                             attn, denom, outb);
    k_norm<<<(N_EDGES * 4) / 256, 256, 0, stream>>>(attn, denom, dstI);
    k_stats<<<(N_NODES + 31) / 32, 256, 0, stream>>>(outb, batch, gsum, gsq, gcnt);
    k_final<<<Y_SIZE / 256, 256, 0, stream>>>(outb, batch, gsum, gsq, gcnt,
                                              lnw, lnb, outp);
}

// Round 8
// 240.348 us; speedup vs baseline: 3.0522x; 1.1081x over previous
//
#include <hip/hip_runtime.h>
#include <hip/hip_fp16.h>

constexpr int N_NODES = 50000;
constexpr int N_EDGES = 800000;
constexpr int HIDDEN  = 128;
constexpr float RSQRT_D = 0.17677669529663687f;  // 1/sqrt(32)
constexpr int Y_SIZE = N_NODES * HIDDEN;         // 6,400,000
constexpr int M_PAD  = 50048;                    // 391 * 128
constexpr int SCAN_BLOCKS = 196;                 // 196*256 = 50176 >= N_NODES
constexpr int XCVT_BLOCKS = (M_PAD * 16) / 256;  // 3128
constexpr int HIST_BLOCKS = N_EDGES / 256;       // 3125

// ---- ws layout (float offsets) ----
constexpr size_t OFF_Q      = 0;         // fp16 qb (12.8 MB of 25.6 slot)
constexpr size_t OFF_K      = 6400000;   // fp16 kv interleaved [node][256]: 25.6 MB (full slot)
constexpr size_t OFF_V      = 12800000;  // (absorbed by kv)
constexpr size_t OFF_S      = 19200000;  // fp16 sb (12.8 MB of slot)
constexpr size_t OFF_DENOM  = 25600000;  // N*4 floats; ALSO hosts Wt_swz (dead before k_fused)
constexpr size_t OFF_GSUM   = 25800000;  // 64
constexpr size_t OFF_GSQ    = 25800064;  // 64
constexpr size_t OFF_GCNT   = 25800128;  // 64 ints
constexpr size_t OFF_DEG    = 25800192;  // 50000 ints
constexpr size_t OFF_OFFS   = 25850192;  // 50001 ints
constexpr size_t OFF_CURSOR = 25900224;  // 50000 ints
constexpr size_t OFF_CSR    = 25950224;  // 800000 int2 (packed src,eid)
constexpr size_t OFF_PART   = 27550224;  // 196 ints (scan partials)

typedef __attribute__((ext_vector_type(8))) short bf16x8;
typedef __attribute__((ext_vector_type(4))) float f32x4;

__device__ __forceinline__ short f2bf(float f) {  // RNE f32 -> bf16 bits
    unsigned u = __float_as_uint(f);
    unsigned r = (u + 0x7fff + ((u >> 16) & 1)) >> 16;
    return (short)r;
}

__device__ __forceinline__ void gload_lds16(const void* g, void* l) {
    __builtin_amdgcn_global_load_lds(
        (const __attribute__((address_space(1))) void*)g,
        (__attribute__((address_space(3))) void*)l, 16, 0, 0);
}

// ---------------- prep: x->bf16 swizzled | W->Wt bf16 swizzled | degree hist ----------------
__global__ __launch_bounds__(256) void k_prep(
    const float* __restrict__ x,
    const float* __restrict__ Wq, const float* __restrict__ Wk,
    const float* __restrict__ Wv, const float* __restrict__ Wsm,
    const int* __restrict__ dst,
    short* __restrict__ xs, short* __restrict__ wt, int* __restrict__ deg)
{
    int b = blockIdx.x;
    if (b < XCVT_BLOCKS) {
        int tid = b * 256 + threadIdx.x;  // M_PAD*16 exact
        int row = tid >> 4, ci = tid & 15;
        short o[8];
        if (row < N_NODES) {
            float4 a = *(const float4*)&x[(size_t)row * 128 + ci * 8];
            float4 bb = *(const float4*)&x[(size_t)row * 128 + ci * 8 + 4];
            o[0] = f2bf(a.x); o[1] = f2bf(a.y); o[2] = f2bf(a.z); o[3] = f2bf(a.w);
            o[4] = f2bf(bb.x); o[5] = f2bf(bb.y); o[6] = f2bf(bb.z); o[7] = f2bf(bb.w);
        } else {
            #pragma unroll
            for (int j = 0; j < 8; ++j) o[j] = 0;
        }
        int cs = ci ^ (row & 7);
        *(int4*)&xs[(size_t)row * 128 + cs * 8] = *(int4*)o;
    } else if (b < XCVT_BLOCKS + 32) {
        int tid = (b - XCVT_BLOCKS) * 256 + threadIdx.x;  // 8192 exact
        int mat = tid >> 11, n = (tid >> 4) & 127, kg = tid & 15;
        const float* W = (mat == 0) ? Wq : (mat == 1) ? Wk : (mat == 2) ? Wv : Wsm;
        short o[8];
        #pragma unroll
        for (int j = 0; j < 8; ++j) o[j] = f2bf(W[(kg * 8 + j) * 128 + n]);
        int cs = kg ^ (n & 7);
        *(int4*)&wt[mat * 16384 + n * 128 + cs * 8] = *(int4*)o;
    } else {
        int e = (b - XCVT_BLOCKS - 32) * 256 + threadIdx.x;  // E exact
        atomicAdd(&deg[dst[e]], 1);
    }
}

// ---------------- MFMA GEMM, single dispatch: all 4 mats per block ----------------
// Block: 256 thr = 4 waves (2x2), 128x128 tile. A staged once, A-frags in regs;
// B re-staged per mat. All outputs fp16; k/v interleaved in kv[node][256].
__global__ __launch_bounds__(256) void k_mm(
    const short* __restrict__ xs, const short* __restrict__ wt,
    const float* __restrict__ bq, const float* __restrict__ bk,
    const float* __restrict__ bv, const float* __restrict__ bs,
    __half* __restrict__ qb, __half* __restrict__ kv, __half* __restrict__ sb)
{
    __shared__ __align__(16) char As[32768];
    __shared__ __align__(16) char Bs[32768];
    const int t = threadIdx.x, lane = t & 63, wv = t >> 6;
    const int m0 = blockIdx.x * 128;
    const int wm = wv >> 1, wn = wv & 1;

    const char* gA = (const char*)xs + (size_t)m0 * 256;
    #pragma unroll
    for (int i = 0; i < 8; ++i) {
        int chunk = wv * 8 + i;
        gload_lds16(gA + chunk * 1024 + lane * 16, As + chunk * 1024);
        gload_lds16((const char*)wt + chunk * 1024 + lane * 16, Bs + chunk * 1024);
    }
    __syncthreads();

    bf16x8 af[4][4];  // [ks][mf], same A for all mats
    #pragma unroll
    for (int ks = 0; ks < 4; ++ks) {
        const int cbase = ks * 64 + ((lane >> 4) << 4);
        #pragma unroll
        for (int mf = 0; mf < 4; ++mf) {
            int mr = wm * 64 + mf * 16 + (lane & 15);
            af[ks][mf] = *(const bf16x8*)(As + mr * 256 + (cbase ^ ((mr & 7) << 4)));
        }
    }

    const float* Bbs[4] = {bq, bk, bv, bs};
    #pragma unroll
    for (int mat = 0; mat < 4; ++mat) {
        f32x4 acc[4][4];
        #pragma unroll
        for (int nf = 0; nf < 4; ++nf) {
            float bc = Bbs[mat][wn * 64 + nf * 16 + (lane & 15)];
            #pragma unroll
            for (int mf = 0; mf < 4; ++mf) acc[mf][nf] = (f32x4){bc, bc, bc, bc};
        }
        #pragma unroll
        for (int ks = 0; ks < 4; ++ks) {
            bf16x8 bfr[4];
            const int cbase = ks * 64 + ((lane >> 4) << 4);
            #pragma unroll
            for (int nf = 0; nf < 4; ++nf) {
                int nc = wn * 64 + nf * 16 + (lane & 15);
                bfr[nf] = *(const bf16x8*)(Bs + nc * 256 + (cbase ^ ((nc & 7) << 4)));
            }
            #pragma unroll
            for (int mf = 0; mf < 4; ++mf)
                #pragma unroll
                for (int nf = 0; nf < 4; ++nf)
                    acc[mf][nf] = __builtin_amdgcn_mfma_f32_16x16x32_bf16(
                        af[ks][mf], bfr[nf], acc[mf][nf], 0, 0, 0);
        }
        __syncthreads();  // all waves done reading Bs
        if (mat < 3) {    // stage next mat's B while we write out
            const char* gB = (const char*)wt + (mat + 1) * 32768;
            #pragma unroll
            for (int i = 0; i < 8; ++i) {
                int chunk = wv * 8 + i;
                gload_lds16(gB + chunk * 1024 + lane * 16, Bs + chunk * 1024);
            }
        }
        // epilogue: all fp16.  mat0->qb[rs=128]  mat1->kv[rs=256]  mat2->kv+128  mat3->sb
        __half* base = (mat == 0) ? qb : (mat == 1) ? kv : (mat == 2) ? (kv + 128) : sb;
        const int rs = (mat == 1 || mat == 2) ? 256 : 128;
        const int colbase = wn * 64 + (lane & 15);
        #pragma unroll
        for (int mf = 0; mf < 4; ++mf) {
            int rowb = m0 + wm * 64 + mf * 16 + ((lane >> 4) << 2);
            #pragma unroll
            for (int nf = 0; nf < 4; ++nf) {
                int col = colbase + nf * 16;
                #pragma unroll
                for (int r = 0; r < 4; ++r) {
                    int node = rowb + r;
                    if (node < N_NODES)
                        base[(size_t)node * rs + col] = __float2half_rn(acc[mf][nf][r]);
                }
            }
        }
        __syncthreads();  // staged Bs complete before next mat's reads
    }
}

// ---------------- 3-phase parallel scan / scatter ----------------
__global__ __launch_bounds__(256) void k_scan1(const int* __restrict__ deg,
                                               int* __restrict__ part)
{
    const int t = threadIdx.x;
    int idx = blockIdx.x * 256 + t;
    int v = (idx < N_NODES) ? deg[idx] : 0;
    #pragma unroll
    for (int o = 1; o < 64; o <<= 1) v += __shfl_xor(v, o);
    __shared__ int wsum[4];
    if ((t & 63) == 0) wsum[t >> 6] = v;
    __syncthreads();
    if (t == 0) part[blockIdx.x] = wsum[0] + wsum[1] + wsum[2] + wsum[3];
}

__global__ __launch_bounds__(256) void k_scan2(int* __restrict__ part)
{
    __shared__ int buf[256];
    const int t = threadIdx.x;
    int v = (t < SCAN_BLOCKS) ? part[t] : 0;
    buf[t] = v;
    __syncthreads();
    for (int o = 1; o < 256; o <<= 1) {
        int tmp = (t >= o) ? buf[t - o] : 0;
        __syncthreads();
        buf[t] += tmp;
        __syncthreads();
    }
    if (t < SCAN_BLOCKS) part[t] = buf[t] - v;  // exclusive
}

__global__ __launch_bounds__(256) void k_scan3(const int* __restrict__ deg,
                                               const int* __restrict__ part,
                                               int* __restrict__ offs,
                                               int* __restrict__ cursor)
{
    const int t = threadIdx.x;
    const int idx = blockIdx.x * 256 + t;
    const int lane = t & 63, w = t >> 6;
    int v = (idx < N_NODES) ? deg[idx] : 0;
    int inc = v;
    #pragma unroll
    for (int o = 1; o < 64; o <<= 1) {
        int nb = __shfl_up(inc, o);
        if (lane >= o) inc += nb;
    }
    __shared__ int wsum[4];
    if (lane == 63) wsum[w] = inc;
    __syncthreads();
    int wbase = 0;
    #pragma unroll
    for (int i = 0; i < 4; ++i) if (i < w) wbase += wsum[i];
    int excl = part[blockIdx.x] + wbase + inc - v;
    if (idx < N_NODES) {
        offs[idx] = excl;
        cursor[idx] = excl;
    }
    if (idx == 0) offs[N_NODES] = N_EDGES;
}

__global__ __launch_bounds__(256) void k_scatter(
    const int* __restrict__ src, const int* __restrict__ dst,
    int* __restrict__ cursor, int2* __restrict__ csr)
{
    int e = blockIdx.x * 256 + threadIdx.x;  // E exact
    int d = dst[e];
    int pos = atomicAdd(&cursor[d], 1);
    csr[pos] = make_int2(src[e], e);
}

// ---------------- fused: logits + exp + denom + aggregate + skip ----------------
// One 64-lane wave per dst node; lane l owns channels (2l, 2l+1); head = l>>4.
// Unroll 4 (round-7 lesson: unroll 8 -> VGPR 40 -> occupancy 51% -> regression).
__global__ __launch_bounds__(256) void k_fused(
    const __half2* __restrict__ qb, const __half2* __restrict__ kvp,
    const __half2* __restrict__ sb,
    const int* __restrict__ offs, const int2* __restrict__ csr,
    float* __restrict__ exbuf, float* __restrict__ denom,
    float* __restrict__ outb)
{
    const int t = threadIdx.x;
    const int lane = t & 63;
    const int n = blockIdx.x * 4 + (t >> 6);  // grid*4 == N exact
    const int begin = offs[n], end = offs[n + 1];
    const float2 qv = __half22float2(qb[(size_t)n * 64 + lane]);
    const float2 sv = __half22float2(sb[(size_t)n * 64 + lane]);
    const int h = lane >> 4;
    float acc0 = 0.f, acc1 = 0.f, dsum = 0.f;
    int i = begin;
    for (; i + 4 <= end; i += 4) {
        int2 c[4];
        #pragma unroll
        for (int u = 0; u < 4; ++u) c[u] = csr[i + u];
        __half2 kh[4], vh[4];
        #pragma unroll
        for (int u = 0; u < 4; ++u) kh[u] = kvp[(size_t)c[u].x * 128 + lane];
        #pragma unroll
        for (int u = 0; u < 4; ++u) vh[u] = kvp[(size_t)c[u].x * 128 + 64 + lane];
        float p[4];
        #pragma unroll
        for (int u = 0; u < 4; ++u) {
            float2 kf = __half22float2(kh[u]);
            p[u] = qv.x * kf.x + qv.y * kf.y;
        }
        #pragma unroll
        for (int u = 0; u < 4; ++u) p[u] += __shfl_xor(p[u], 1);
        #pragma unroll
        for (int u = 0; u < 4; ++u) p[u] += __shfl_xor(p[u], 2);
        #pragma unroll
        for (int u = 0; u < 4; ++u) p[u] += __shfl_xor(p[u], 4);
        #pragma unroll
        for (int u = 0; u < 4; ++u) p[u] += __shfl_xor(p[u], 8);
        #pragma unroll
        for (int u = 0; u < 4; ++u) {
            float ex = __expf(p[u] * RSQRT_D);
            dsum += ex;
            float2 vf = __half22float2(vh[u]);
            acc0 += ex * vf.x;
            acc1 += ex * vf.y;
            if ((lane & 15) == 0) exbuf[c[u].y * 4 + h] = ex;
        }
    }
    for (; i < end; ++i) {
        const int2 c0 = csr[i];
        const __half2 kh0 = kvp[(size_t)c0.x * 128 + lane];
        const __half2 vh0 = kvp[(size_t)c0.x * 128 + 64 + lane];
        const float2 k0 = __half22float2(kh0);
        float p0 = qv.x * k0.x + qv.y * k0.y;
        p0 += __shfl_xor(p0, 1);
        p0 += __shfl_xor(p0, 2);
        p0 += __shfl_xor(p0, 4);
        p0 += __shfl_xor(p0, 8);
        const float ex0 = __expf(p0 * RSQRT_D);
        dsum += ex0;
        const float2 v0 = __half22float2(vh0);
        acc0 += ex0 * v0.x;
        acc1 += ex0 * v0.y;
        if ((lane & 15) == 0) exbuf[c0.y * 4 + h] = ex0;
    }
    if ((lane & 15) == 0) denom[n * 4 + h] = dsum;
    const float rdn = 1.f / (dsum + 1e-16f);
    float2 o = make_float2(acc0 * rdn + sv.x, acc1 * rdn + sv.y);
    *(float2*)&outb[(size_t)n * 128 + lane * 2] = o;
}

// ---------------- normalize attn in place ----------------
__global__ __launch_bounds__(256) void k_norm(
    float* __restrict__ attn, const float* __restrict__ denom,
    const int* __restrict__ dst)
{
    int idx = blockIdx.x * 256 + threadIdx.x;  // E*4 exact
    int e = idx >> 2, h = idx & 3;
    attn[idx] = attn[idx] / (denom[dst[e] * 4 + h] + 1e-16f);
}

// ---------------- per-graph sum + sumsq + count, one pass ----------------
__global__ __launch_bounds__(256) void k_stats(
    const float* __restrict__ out, const int* __restrict__ batch,
    float* __restrict__ gsum, float* __restrict__ gsq, int* __restrict__ gcnt)
{
    __shared__ float nsum[32], nsq[32];
    __shared__ int   ngr[32];
    const int t = threadIdx.x;
    const int nl = t >> 3, part = t & 7;
    const int n = blockIdx.x * 32 + nl;
    float lsum = 0.f, lsq = 0.f;
    if (n < N_NODES) {
        size_t base = (size_t)n * 128 + part * 16;
        #pragma unroll
        for (int i = 0; i < 4; ++i) {
            float4 o = *(const float4*)&out[base + i * 4];
            lsum += o.x + o.y + o.z + o.w;
            lsq  += o.x * o.x + o.y * o.y + o.z * o.z + o.w * o.w;
        }
    }
    #pragma unroll
    for (int o = 1; o < 8; o <<= 1) {
        lsum += __shfl_xor(lsum, o);
        lsq  += __shfl_xor(lsq, o);
    }
    if (part == 0) { nsum[nl] = lsum; nsq[nl] = lsq; ngr[nl] = (n < N_NODES) ? batch[n] : -1; }
    __syncthreads();
    if (t == 0) {
        float acc = 0.f, accq = 0.f; int cg = ngr[0], cnt = 0;
        for (int i = 0; i < 32; ++i) {
            int g = ngr[i];
            if (g != cg) {
                if (cg >= 0) { atomicAdd(&gsum[cg], acc); atomicAdd(&gsq[cg], accq);
                               atomicAdd(&gcnt[cg], cnt); }
                acc = 0.f; accq = 0.f; cnt = 0; cg = g;
            }
            acc += nsum[i]; accq += nsq[i]; ++cnt;
        }
        if (cg >= 0) { atomicAdd(&gsum[cg], acc); atomicAdd(&gsq[cg], accq);
                       atomicAdd(&gcnt[cg], cnt); }
    }
}

// ---------------- LayerNorm affine + LeakyReLU (in-place) ----------------
__global__ __launch_bounds__(256) void k_final(
    const float* __restrict__ out, const int* __restrict__ batch,
    const float* __restrict__ gsum, const float* __restrict__ gsq,
    const int* __restrict__ gcnt,
    const float* __restrict__ lnw, const float* __restrict__ lnb,
    float* __restrict__ y)
{
    int idx = blockIdx.x * 256 + threadIdx.x;  // N*128 exact
    int n = idx >> 7, c = idx & 127;
    int g = batch[n];
    float norm = fmaxf((float)gcnt[g], 1.f) * 128.f;
    float mean = gsum[g] / norm;
    float var  = gsq[g] / norm - mean * mean;
    float inv  = rsqrtf(var + 1e-5f);
    float val  = (out[idx] - mean) * inv * lnw[c] + lnb[c];
    y[idx] = val > 0.f ? val : 0.01f * val;
}

extern "C" void kernel_launch(void* const* d_in, const int* in_sizes, int n_in,
                              void* d_out, int out_size, void* d_ws, size_t ws_size,
                              hipStream_t stream)
{
    (void)in_sizes; (void)n_in; (void)out_size; (void)ws_size;
    const float* x    = (const float*)d_in[0];
    const int*   ei   = (const int*)  d_in[1];
    const int*   batch= (const int*)  d_in[2];
    const float* Wq   = (const float*)d_in[3];
    const float* bq   = (const float*)d_in[4];
    const float* Wk   = (const float*)d_in[5];
    const float* bk   = (const float*)d_in[6];
    const float* Wv   = (const float*)d_in[7];
    const float* bv   = (const float*)d_in[8];
    const float* Wsm  = (const float*)d_in[9];
    const float* bs   = (const float*)d_in[10];
    const float* lnw  = (const float*)d_in[11];
    const float* lnb  = (const float*)d_in[12];

    float* outp = (float*)d_out;
    float* ws   = (float*)d_ws;

    const int* srcI = ei;
    const int* dstI = ei + N_EDGES;

    __half* qb      = (__half*)(ws + OFF_Q);
    __half* kv      = (__half*)(ws + OFF_K);
    __half* sb      = (__half*)(ws + OFF_S);
    float*  denom   = ws + OFF_DENOM;
    short*  wt      = (short*)(ws + OFF_DENOM);  // dead before k_fused writes denom
    float*  gsum    = ws + OFF_GSUM;
    float*  gsq     = ws + OFF_GSQ;
    int*    gcnt    = (int*)(ws + OFF_GCNT);
    int*    deg     = (int*)(ws + OFF_DEG);
    int*    offs    = (int*)(ws + OFF_OFFS);
    int*    cursor  = (int*)(ws + OFF_CURSOR);
    int2*   csr     = (int2*)(ws + OFF_CSR);
    int*    partArr = (int*)(ws + OFF_PART);

    float* outb  = outp;                  // y region: x_swz first, then pre-LN out
    short* x_swz = (short*)outp;          // 12.8 MB, dead once k_mm finishes
    float* attn  = outp + Y_SIZE;

    // zero gsum/gsq/gcnt + deg (contiguous)
    hipMemsetAsync(gsum, 0, (size_t)(192 + N_NODES) * sizeof(float), stream);

    k_prep<<<XCVT_BLOCKS + 32 + HIST_BLOCKS, 256, 0, stream>>>(
        x, Wq, Wk, Wv, Wsm, dstI, x_swz, wt, deg);
    k_mm<<<M_PAD / 128, 256, 0, stream>>>(x_swz, wt, bq, bk, bv, bs, qb, kv, sb);

    k_scan1<<<SCAN_BLOCKS, 256, 0, stream>>>(deg, partArr);
    k_scan2<<<1, 256, 0, stream>>>(partArr);
    k_scan3<<<SCAN_BLOCKS, 256, 0, stream>>>(deg, partArr, offs, cursor);
    k_scatter<<<N_EDGES / 256, 256, 0, stream>>>(srcI, dstI, cursor, csr);
    k_fused<<<N_NODES / 4, 256, 0, stream>>>((const __half2*)qb, (const __half2*)kv,
                                             (const __half2*)sb, offs, csr,
                                             attn, denom, outb);
    k_norm<<<(N_EDGES * 4) / 256, 256, 0, stream>>>(attn, denom, dstI);
    k_stats<<<(N_NODES + 31) / 32, 256, 0, stream>>>(outb, batch, gsum, gsq, gcnt);
    k_final<<<Y_SIZE / 256, 256, 0, stream>>>(outb, batch, gsum, gsq, gcnt,
                                              lnw, lnb, outp);
}

// Round 9
// 230.848 us; speedup vs baseline: 3.1778x; 1.0411x over previous
//
#include <hip/hip_runtime.h>
#include <hip/hip_fp16.h>

constexpr int N_NODES = 50000;
constexpr int N_EDGES = 800000;
constexpr int HIDDEN  = 128;
constexpr float RSQRT_D = 0.17677669529663687f;  // 1/sqrt(32)
constexpr int Y_SIZE = N_NODES * HIDDEN;         // 6,400,000
constexpr int M_PAD  = 50048;                    // 391 * 128
constexpr int SCAN_BLOCKS = 196;                 // 196*256 = 50176 >= N_NODES
constexpr int XCVT_BLOCKS = (M_PAD * 16) / 256;  // 3128
constexpr int HIST_BLOCKS = N_EDGES / 256;       // 3125
constexpr int NORM_BLOCKS = (N_EDGES * 4) / 256; // 12500
constexpr int STAT_BLOCKS = (N_NODES + 31) / 32; // 1563

// ---- ws layout (float offsets) ----
constexpr size_t OFF_Q      = 0;         // fp16 qb (12.8 MB of 25.6 slot)
constexpr size_t OFF_K      = 6400000;   // fp16 kv interleaved [node][256]: 25.6 MB
constexpr size_t OFF_S      = 19200000;  // fp16 sb
constexpr size_t OFF_DENOM  = 25600000;  // N*4 floats; ALSO hosts Wt_swz (dead before k_fused)
constexpr size_t OFF_GSUM   = 25800000;  // 64
constexpr size_t OFF_GSQ    = 25800064;  // 64
constexpr size_t OFF_GCNT   = 25800128;  // 64 ints
constexpr size_t OFF_DEG    = 25800192;  // 50000 ints
constexpr size_t OFF_OFFS   = 25850192;  // 50001 ints
constexpr size_t OFF_CURSOR = 25900224;  // 50000 ints
constexpr size_t OFF_CSR    = 25950224;  // 800000 int2 (packed src,eid)
constexpr size_t OFF_PART   = 27550224;  // 196 ints (scan partials)

typedef __attribute__((ext_vector_type(8))) short bf16x8;
typedef __attribute__((ext_vector_type(4))) float f32x4;

__device__ __forceinline__ short f2bf(float f) {  // RNE f32 -> bf16 bits
    unsigned u = __float_as_uint(f);
    unsigned r = (u + 0x7fff + ((u >> 16) & 1)) >> 16;
    return (short)r;
}

__device__ __forceinline__ void gload_lds16(const void* g, void* l) {
    __builtin_amdgcn_global_load_lds(
        (const __attribute__((address_space(1))) void*)g,
        (__attribute__((address_space(3))) void*)l, 16, 0, 0);
}

// ---------------- prep: x->bf16 swizzled | W->Wt bf16 swizzled | degree hist ----------------
__global__ __launch_bounds__(256) void k_prep(
    const float* __restrict__ x,
    const float* __restrict__ Wq, const float* __restrict__ Wk,
    const float* __restrict__ Wv, const float* __restrict__ Wsm,
    const int* __restrict__ dst,
    short* __restrict__ xs, short* __restrict__ wt, int* __restrict__ deg)
{
    int b = blockIdx.x;
    if (b < XCVT_BLOCKS) {
        int tid = b * 256 + threadIdx.x;  // M_PAD*16 exact
        int row = tid >> 4, ci = tid & 15;
        short o[8];
        if (row < N_NODES) {
            float4 a = *(const float4*)&x[(size_t)row * 128 + ci * 8];
            float4 bb = *(const float4*)&x[(size_t)row * 128 + ci * 8 + 4];
            o[0] = f2bf(a.x); o[1] = f2bf(a.y); o[2] = f2bf(a.z); o[3] = f2bf(a.w);
            o[4] = f2bf(bb.x); o[5] = f2bf(bb.y); o[6] = f2bf(bb.z); o[7] = f2bf(bb.w);
        } else {
            #pragma unroll
            for (int j = 0; j < 8; ++j) o[j] = 0;
        }
        int cs = ci ^ (row & 7);
        *(int4*)&xs[(size_t)row * 128 + cs * 8] = *(int4*)o;
    } else if (b < XCVT_BLOCKS + 32) {
        int tid = (b - XCVT_BLOCKS) * 256 + threadIdx.x;  // 8192 exact
        int mat = tid >> 11, n = (tid >> 4) & 127, kg = tid & 15;
        const float* W = (mat == 0) ? Wq : (mat == 1) ? Wk : (mat == 2) ? Wv : Wsm;
        short o[8];
        #pragma unroll
        for (int j = 0; j < 8; ++j) o[j] = f2bf(W[(kg * 8 + j) * 128 + n]);
        int cs = kg ^ (n & 7);
        *(int4*)&wt[mat * 16384 + n * 128 + cs * 8] = *(int4*)o;
    } else {
        int e = (b - XCVT_BLOCKS - 32) * 256 + threadIdx.x;  // E exact
        atomicAdd(&deg[dst[e]], 1);
    }
}

// ---------------- MFMA GEMM, single dispatch: all 4 mats per block ----------------
__global__ __launch_bounds__(256) void k_mm(
    const short* __restrict__ xs, const short* __restrict__ wt,
    const float* __restrict__ bq, const float* __restrict__ bk,
    const float* __restrict__ bv, const float* __restrict__ bs,
    __half* __restrict__ qb, __half* __restrict__ kv, __half* __restrict__ sb)
{
    __shared__ __align__(16) char As[32768];
    __shared__ __align__(16) char Bs[32768];
    const int t = threadIdx.x, lane = t & 63, wv = t >> 6;
    const int m0 = blockIdx.x * 128;
    const int wm = wv >> 1, wn = wv & 1;

    const char* gA = (const char*)xs + (size_t)m0 * 256;
    #pragma unroll
    for (int i = 0; i < 8; ++i) {
        int chunk = wv * 8 + i;
        gload_lds16(gA + chunk * 1024 + lane * 16, As + chunk * 1024);
        gload_lds16((const char*)wt + chunk * 1024 + lane * 16, Bs + chunk * 1024);
    }
    __syncthreads();

    bf16x8 af[4][4];  // [ks][mf], same A for all mats
    #pragma unroll
    for (int ks = 0; ks < 4; ++ks) {
        const int cbase = ks * 64 + ((lane >> 4) << 4);
        #pragma unroll
        for (int mf = 0; mf < 4; ++mf) {
            int mr = wm * 64 + mf * 16 + (lane & 15);
            af[ks][mf] = *(const bf16x8*)(As + mr * 256 + (cbase ^ ((mr & 7) << 4)));
        }
    }

    const float* Bbs[4] = {bq, bk, bv, bs};
    #pragma unroll
    for (int mat = 0; mat < 4; ++mat) {
        f32x4 acc[4][4];
        #pragma unroll
        for (int nf = 0; nf < 4; ++nf) {
            float bc = Bbs[mat][wn * 64 + nf * 16 + (lane & 15)];
            #pragma unroll
            for (int mf = 0; mf < 4; ++mf) acc[mf][nf] = (f32x4){bc, bc, bc, bc};
        }
        #pragma unroll
        for (int ks = 0; ks < 4; ++ks) {
            bf16x8 bfr[4];
            const int cbase = ks * 64 + ((lane >> 4) << 4);
            #pragma unroll
            for (int nf = 0; nf < 4; ++nf) {
                int nc = wn * 64 + nf * 16 + (lane & 15);
                bfr[nf] = *(const bf16x8*)(Bs + nc * 256 + (cbase ^ ((nc & 7) << 4)));
            }
            #pragma unroll
            for (int mf = 0; mf < 4; ++mf)
                #pragma unroll
                for (int nf = 0; nf < 4; ++nf)
                    acc[mf][nf] = __builtin_amdgcn_mfma_f32_16x16x32_bf16(
                        af[ks][mf], bfr[nf], acc[mf][nf], 0, 0, 0);
        }
        __syncthreads();  // all waves done reading Bs
        if (mat < 3) {    // stage next mat's B while we write out
            const char* gB = (const char*)wt + (mat + 1) * 32768;
            #pragma unroll
            for (int i = 0; i < 8; ++i) {
                int chunk = wv * 8 + i;
                gload_lds16(gB + chunk * 1024 + lane * 16, Bs + chunk * 1024);
            }
        }
        __half* base = (mat == 0) ? qb : (mat == 1) ? kv : (mat == 2) ? (kv + 128) : sb;
        const int rs = (mat == 1 || mat == 2) ? 256 : 128;
        const int colbase = wn * 64 + (lane & 15);
        #pragma unroll
        for (int mf = 0; mf < 4; ++mf) {
            int rowb = m0 + wm * 64 + mf * 16 + ((lane >> 4) << 2);
            #pragma unroll
            for (int nf = 0; nf < 4; ++nf) {
                int col = colbase + nf * 16;
                #pragma unroll
                for (int r = 0; r < 4; ++r) {
                    int node = rowb + r;
                    if (node < N_NODES)
                        base[(size_t)node * rs + col] = __float2half_rn(acc[mf][nf][r]);
                }
            }
        }
        __syncthreads();  // staged Bs complete before next mat's reads
    }
}

// ---------------- 3-phase parallel scan / scatter ----------------
__global__ __launch_bounds__(256) void k_scan1(const int* __restrict__ deg,
                                               int* __restrict__ part)
{
    const int t = threadIdx.x;
    int idx = blockIdx.x * 256 + t;
    int v = (idx < N_NODES) ? deg[idx] : 0;
    #pragma unroll
    for (int o = 1; o < 64; o <<= 1) v += __shfl_xor(v, o);
    __shared__ int wsum[4];
    if ((t & 63) == 0) wsum[t >> 6] = v;
    __syncthreads();
    if (t == 0) part[blockIdx.x] = wsum[0] + wsum[1] + wsum[2] + wsum[3];
}

__global__ __launch_bounds__(256) void k_scan2(int* __restrict__ part)
{
    __shared__ int buf[256];
    const int t = threadIdx.x;
    int v = (t < SCAN_BLOCKS) ? part[t] : 0;
    buf[t] = v;
    __syncthreads();
    for (int o = 1; o < 256; o <<= 1) {
        int tmp = (t >= o) ? buf[t - o] : 0;
        __syncthreads();
        buf[t] += tmp;
        __syncthreads();
    }
    if (t < SCAN_BLOCKS) part[t] = buf[t] - v;  // exclusive
}

__global__ __launch_bounds__(256) void k_scan3(const int* __restrict__ deg,
                                               const int* __restrict__ part,
                                               int* __restrict__ offs,
                                               int* __restrict__ cursor)
{
    const int t = threadIdx.x;
    const int idx = blockIdx.x * 256 + t;
    const int lane = t & 63, w = t >> 6;
    int v = (idx < N_NODES) ? deg[idx] : 0;
    int inc = v;
    #pragma unroll
    for (int o = 1; o < 64; o <<= 1) {
        int nb = __shfl_up(inc, o);
        if (lane >= o) inc += nb;
    }
    __shared__ int wsum[4];
    if (lane == 63) wsum[w] = inc;
    __syncthreads();
    int wbase = 0;
    #pragma unroll
    for (int i = 0; i < 4; ++i) if (i < w) wbase += wsum[i];
    int excl = part[blockIdx.x] + wbase + inc - v;
    if (idx < N_NODES) {
        offs[idx] = excl;
        cursor[idx] = excl;
    }
    if (idx == 0) offs[N_NODES] = N_EDGES;
}

__global__ __launch_bounds__(256) void k_scatter(
    const int* __restrict__ src, const int* __restrict__ dst,
    int* __restrict__ cursor, int2* __restrict__ csr)
{
    int e = blockIdx.x * 256 + threadIdx.x;  // E exact
    int d = dst[e];
    int pos = atomicAdd(&cursor[d], 1);
    csr[pos] = make_int2(src[e], e);
}

// ---------------- fused: logits + exp + denom + aggregate + skip ----------------
// One 64-lane wave per dst node. 16 lanes per edge (8 ch/lane), 4 edges per
// wave-iteration: 2-step shfl reduce over 4-lane head groups; quarter sums
// combined once at the end. (Round-8: 64-lane/edge had 48% VALUBusy from
// 4-step shfl + 64x redundant exp.)
__global__ __launch_bounds__(256) void k_fused(
    const __half* __restrict__ qb, const __half* __restrict__ kv,
    const __half* __restrict__ sb,
    const int* __restrict__ offs, const int2* __restrict__ csr,
    float* __restrict__ exbuf, float* __restrict__ denom,
    float* __restrict__ outb)
{
    const int t = threadIdx.x;
    const int lane = t & 63;
    const int n = blockIdx.x * 4 + (t >> 6);  // grid*4 == N exact
    const int begin = offs[n], end = offs[n + 1];
    const int cl  = lane & 15;   // owns channels [cl*8, cl*8+8)
    const int qtr = lane >> 4;   // edge slot within 4-group
    const int h   = cl >> 2;     // head of this lane's channels

    const __half2* qp = (const __half2*)(qb + (size_t)n * 128 + cl * 8);
    float2 qf[4];
    #pragma unroll
    for (int j = 0; j < 4; ++j) qf[j] = __half22float2(qp[j]);

    float acc[8] = {0.f, 0.f, 0.f, 0.f, 0.f, 0.f, 0.f, 0.f};
    float dsum = 0.f;
    int i = begin;
    for (; i + 8 <= end; i += 8) {  // two 4-edge groups, unguarded
        const int2 c0 = csr[i + qtr];
        const int2 c1 = csr[i + 4 + qtr];
        const __half2* k0 = (const __half2*)(kv + (size_t)c0.x * 256 + cl * 8);
        const __half2* k1 = (const __half2*)(kv + (size_t)c1.x * 256 + cl * 8);
        __half2 ka[4], kb2[4], va[4], vb2[4];
        #pragma unroll
        for (int j = 0; j < 4; ++j) { ka[j] = k0[j]; va[j] = k0[64 + j]; }
        #pragma unroll
        for (int j = 0; j < 4; ++j) { kb2[j] = k1[j]; vb2[j] = k1[64 + j]; }
        float p0 = 0.f, p1 = 0.f;
        #pragma unroll
        for (int j = 0; j < 4; ++j) {
            float2 f0 = __half22float2(ka[j]), f1 = __half22float2(kb2[j]);
            p0 += qf[j].x * f0.x + qf[j].y * f0.y;
            p1 += qf[j].x * f1.x + qf[j].y * f1.y;
        }
        p0 += __shfl_xor(p0, 1);  p1 += __shfl_xor(p1, 1);
        p0 += __shfl_xor(p0, 2);  p1 += __shfl_xor(p1, 2);
        const float ex0 = __expf(p0 * RSQRT_D);
        const float ex1 = __expf(p1 * RSQRT_D);
        dsum += ex0 + ex1;
        #pragma unroll
        for (int j = 0; j < 4; ++j) {
            float2 f0 = __half22float2(va[j]), f1 = __half22float2(vb2[j]);
            acc[2*j]   += ex0 * f0.x + ex1 * f1.x;
            acc[2*j+1] += ex0 * f0.y + ex1 * f1.y;
        }
        if ((lane & 3) == 0) {
            exbuf[c0.y * 4 + h] = ex0;
            exbuf[c1.y * 4 + h] = ex1;
        }
    }
    for (; i < end; i += 4) {  // guarded 4-edge tail
        const int eIdx = i + qtr;
        const bool act = eIdx < end;
        const int2 c0 = csr[act ? eIdx : end - 1];
        const __half2* k0 = (const __half2*)(kv + (size_t)c0.x * 256 + cl * 8);
        __half2 ka[4], va[4];
        #pragma unroll
        for (int j = 0; j < 4; ++j) { ka[j] = k0[j]; va[j] = k0[64 + j]; }
        float p0 = 0.f;
        #pragma unroll
        for (int j = 0; j < 4; ++j) {
            float2 f0 = __half22float2(ka[j]);
            p0 += qf[j].x * f0.x + qf[j].y * f0.y;
        }
        p0 += __shfl_xor(p0, 1);
        p0 += __shfl_xor(p0, 2);
        const float ex0 = act ? __expf(p0 * RSQRT_D) : 0.f;
        dsum += ex0;
        #pragma unroll
        for (int j = 0; j < 4; ++j) {
            float2 f0 = __half22float2(va[j]);
            acc[2*j]   += ex0 * f0.x;
            acc[2*j+1] += ex0 * f0.y;
        }
        if (((lane & 3) == 0) && act) exbuf[c0.y * 4 + h] = ex0;
    }
    // combine the 4 edge-quarters (lanes l, l+16, l+32, l+48 share channels)
    dsum += __shfl_xor(dsum, 16);
    dsum += __shfl_xor(dsum, 32);
    #pragma unroll
    for (int j = 0; j < 8; ++j) {
        acc[j] += __shfl_xor(acc[j], 16);
        acc[j] += __shfl_xor(acc[j], 32);
    }
    if (lane < 16) {
        if ((lane & 3) == 0) denom[n * 4 + h] = dsum;
        const float rdn = 1.f / (dsum + 1e-16f);
        const __half2* sp = (const __half2*)(sb + (size_t)n * 128 + cl * 8);
        float o[8];
        #pragma unroll
        for (int j = 0; j < 4; ++j) {
            float2 sf = __half22float2(sp[j]);
            o[2*j]   = acc[2*j]   * rdn + sf.x;
            o[2*j+1] = acc[2*j+1] * rdn + sf.y;
        }
        *(float4*)&outb[(size_t)n * 128 + cl * 8]     = make_float4(o[0], o[1], o[2], o[3]);
        *(float4*)&outb[(size_t)n * 128 + cl * 8 + 4] = make_float4(o[4], o[5], o[6], o[7]);
    }
}

// ---------------- merged: attn normalize | per-graph stats ----------------
__global__ __launch_bounds__(256) void k_post(
    float* __restrict__ attn, const float* __restrict__ denom,
    const int* __restrict__ dst,
    const float* __restrict__ out, const int* __restrict__ batch,
    float* __restrict__ gsum, float* __restrict__ gsq, int* __restrict__ gcnt)
{
    const int b = blockIdx.x;
    if (b < NORM_BLOCKS) {
        int idx = b * 256 + threadIdx.x;  // E*4 exact
        int e = idx >> 2, h = idx & 3;
        attn[idx] = attn[idx] / (denom[dst[e] * 4 + h] + 1e-16f);
        return;
    }
    __shared__ float nsum[32], nsq[32];
    __shared__ int   ngr[32];
    const int t = threadIdx.x;
    const int nl = t >> 3, part = t & 7;
    const int n = (b - NORM_BLOCKS) * 32 + nl;
    float lsum = 0.f, lsq = 0.f;
    if (n < N_NODES) {
        size_t base = (size_t)n * 128 + part * 16;
        #pragma unroll
        for (int i = 0; i < 4; ++i) {
            float4 o = *(const float4*)&out[base + i * 4];
            lsum += o.x + o.y + o.z + o.w;
            lsq  += o.x * o.x + o.y * o.y + o.z * o.z + o.w * o.w;
        }
    }
    #pragma unroll
    for (int o = 1; o < 8; o <<= 1) {
        lsum += __shfl_xor(lsum, o);
        lsq  += __shfl_xor(lsq, o);
    }
    if (part == 0) { nsum[nl] = lsum; nsq[nl] = lsq; ngr[nl] = (n < N_NODES) ? batch[n] : -1; }
    __syncthreads();
    if (t == 0) {
        float acc = 0.f, accq = 0.f; int cg = ngr[0], cnt = 0;
        for (int i = 0; i < 32; ++i) {
            int g = ngr[i];
            if (g != cg) {
                if (cg >= 0) { atomicAdd(&gsum[cg], acc); atomicAdd(&gsq[cg], accq);
                               atomicAdd(&gcnt[cg], cnt); }
                acc = 0.f; accq = 0.f; cnt = 0; cg = g;
            }
            acc += nsum[i]; accq += nsq[i]; ++cnt;
        }
        if (cg >= 0) { atomicAdd(&gsum[cg], acc); atomicAdd(&gsq[cg], accq);
                       atomicAdd(&gcnt[cg], cnt); }
    }
}

// ---------------- LayerNorm affine + LeakyReLU (in-place) ----------------
__global__ __launch_bounds__(256) void k_final(
    const float* __restrict__ out, const int* __restrict__ batch,
    const float* __restrict__ gsum, const float* __restrict__ gsq,
    const int* __restrict__ gcnt,
    const float* __restrict__ lnw, const float* __restrict__ lnb,
    float* __restrict__ y)
{
    int idx = blockIdx.x * 256 + threadIdx.x;  // N*128 exact
    int n = idx >> 7, c = idx & 127;
    int g = batch[n];
    float norm = fmaxf((float)gcnt[g], 1.f) * 128.f;
    float mean = gsum[g] / norm;
    float var  = gsq[g] / norm - mean * mean;
    float inv  = rsqrtf(var + 1e-5f);
    float val  = (out[idx] - mean) * inv * lnw[c] + lnb[c];
    y[idx] = val > 0.f ? val : 0.01f * val;
}

extern "C" void kernel_launch(void* const* d_in, const int* in_sizes, int n_in,
                              void* d_out, int out_size, void* d_ws, size_t ws_size,
                              hipStream_t stream)
{
    (void)in_sizes; (void)n_in; (void)out_size; (void)ws_size;
    const float* x    = (const float*)d_in[0];
    const int*   ei   = (const int*)  d_in[1];
    const int*   batch= (const int*)  d_in[2];
    const float* Wq   = (const float*)d_in[3];
    const float* bq   = (const float*)d_in[4];
    const float* Wk   = (const float*)d_in[5];
    const float* bk   = (const float*)d_in[6];
    const float* Wv   = (const float*)d_in[7];
    const float* bv   = (const float*)d_in[8];
    const float* Wsm  = (const float*)d_in[9];
    const float* bs   = (const float*)d_in[10];
    const float* lnw  = (const float*)d_in[11];
    const float* lnb  = (const float*)d_in[12];

    float* outp = (float*)d_out;
    float* ws   = (float*)d_ws;

    const int* srcI = ei;
    const int* dstI = ei + N_EDGES;

    __half* qb      = (__half*)(ws + OFF_Q);
    __half* kv      = (__half*)(ws + OFF_K);
    __half* sb      = (__half*)(ws + OFF_S);
    float*  denom   = ws + OFF_DENOM;
    short*  wt      = (short*)(ws + OFF_DENOM);  // dead before k_fused writes denom
    float*  gsum    = ws + OFF_GSUM;
    float*  gsq     = ws + OFF_GSQ;
    int*    gcnt    = (int*)(ws + OFF_GCNT);
    int*    deg     = (int*)(ws + OFF_DEG);
    int*    offs    = (int*)(ws + OFF_OFFS);
    int*    cursor  = (int*)(ws + OFF_CURSOR);
    int2*   csr     = (int2*)(ws + OFF_CSR);
    int*    partArr = (int*)(ws + OFF_PART);

    float* outb  = outp;                  // y region: x_swz first, then pre-LN out
    short* x_swz = (short*)outp;          // 12.8 MB, dead once k_mm finishes
    float* attn  = outp + Y_SIZE;

    // zero gsum/gsq/gcnt + deg (contiguous)
    hipMemsetAsync(gsum, 0, (size_t)(192 + N_NODES) * sizeof(float), stream);

    k_prep<<<XCVT_BLOCKS + 32 + HIST_BLOCKS, 256, 0, stream>>>(
        x, Wq, Wk, Wv, Wsm, dstI, x_swz, wt, deg);
    k_mm<<<M_PAD / 128, 256, 0, stream>>>(x_swz, wt, bq, bk, bv, bs, qb, kv, sb);

    k_scan1<<<SCAN_BLOCKS, 256, 0, stream>>>(deg, partArr);
    k_scan2<<<1, 256, 0, stream>>>(partArr);
    k_scan3<<<SCAN_BLOCKS, 256, 0, stream>>>(deg, partArr, offs, cursor);
    k_scatter<<<N_EDGES / 256, 256, 0, stream>>>(srcI, dstI, cursor, csr);
    k_fused<<<N_NODES / 4, 256, 0, stream>>>(qb, kv, sb, offs, csr,
                                             attn, denom, outb);
    k_post<<<NORM_BLOCKS + STAT_BLOCKS, 256, 0, stream>>>(
        attn, denom, dstI, outb, batch, gsum, gsq, gcnt);
    k_final<<<Y_SIZE / 256, 256, 0, stream>>>(outb, batch, gsum, gsq, gcnt,
                                              lnw, lnb, outp);
}